// Round 1
// baseline (1094.534 us; speedup 1.0000x reference)
//
#include <hip/hip_runtime.h>
#include <math.h>

namespace {
constexpr int B_  = 64;
constexpr int T_  = 1380;
constexpr int XD_ = 96;
constexpr int HD_ = 192;
constexpr int CN_ = 345;
constexpr float SCALE_ = 0.00736569563735987f; // 1/sqrt(96*192)
}

// ---------------------------------------------------------------------------
// K1: Zp[sp][b][c][x] = sum_{t in half sp} W2[c,t] * X[b,t,x]
// grid (6, B, 2), block 256. c-tile 64 (4 per thread), x-tile 96 (6 per thread)
// ---------------------------------------------------------------------------
__global__ __launch_bounds__(256) void k1_w2x(const float* __restrict__ X,
                                              const float* __restrict__ W2,
                                              float* __restrict__ Zp) {
    __shared__ __align__(16) float W2t[15][68];   // [k][c], padded
    __shared__ __align__(16) float Xt[15][XD_];   // [k][x]
    const int tid = threadIdx.x;
    const int tx = tid & 15, ty = tid >> 4;
    const int c0 = blockIdx.x * 64;
    const int b  = blockIdx.y;
    const int sp = blockIdx.z;
    const int tbase = sp * (T_ / 2);

    float acc[4][6];
#pragma unroll
    for (int i = 0; i < 4; i++)
#pragma unroll
        for (int j = 0; j < 6; j++) acc[i][j] = 0.f;

    for (int k0 = 0; k0 < T_ / 2; k0 += 15) {
        __syncthreads();
        for (int idx = tid; idx < 64 * 15; idx += 256) {
            int c = idx / 15, k = idx % 15;
            float v = 0.f;
            if (c0 + c < CN_) v = W2[(size_t)(c0 + c) * T_ + tbase + k0 + k];
            W2t[k][c] = v;
        }
        for (int idx = tid; idx < 15 * XD_; idx += 256) {
            int k = idx / XD_, x = idx % XD_;
            Xt[k][x] = X[((size_t)b * T_ + tbase + k0 + k) * XD_ + x];
        }
        __syncthreads();
#pragma unroll
        for (int kk = 0; kk < 15; kk++) {
            float4 a = *(const float4*)&W2t[kk][4 * ty];
            float bv[6];
#pragma unroll
            for (int j = 0; j < 6; j++) bv[j] = Xt[kk][6 * tx + j];
#pragma unroll
            for (int j = 0; j < 6; j++) {
                acc[0][j] += a.x * bv[j];
                acc[1][j] += a.y * bv[j];
                acc[2][j] += a.z * bv[j];
                acc[3][j] += a.w * bv[j];
            }
        }
    }
    float* Zb = Zp + ((size_t)sp * B_ + b) * CN_ * XD_;
#pragma unroll
    for (int i = 0; i < 4; i++) {
        int c = c0 + 4 * ty + i;
        if (c < CN_) {
#pragma unroll
            for (int j = 0; j < 6; j++) Zb[(size_t)c * XD_ + 6 * tx + j] = acc[i][j];
        }
    }
}

// ---------------------------------------------------------------------------
// K2: Ys[b][c][h] = SCALE * sum_x (Zp0+Zp1)[b][c][x] * W1[x][h]
// grid (11, B), block 256. c-tile 32 (2/thread), h-tile 192 (12/thread)
// ---------------------------------------------------------------------------
__global__ __launch_bounds__(256) void k2_zw1(const float* __restrict__ Zp,
                                              const float* __restrict__ W1,
                                              float* __restrict__ Ysg) {
    __shared__ __align__(16) float Zt[32][100];    // [c][x], padded
    __shared__ __align__(16) float W1c[16][HD_];   // [k][h]
    const int tid = threadIdx.x;
    const int tx = tid & 15, ty = tid >> 4;
    const int c0 = blockIdx.x * 32;
    const int b  = blockIdx.y;
    const float* Z0 = Zp + (size_t)b * CN_ * XD_;
    const float* Z1 = Zp + (size_t)(B_ + b) * CN_ * XD_;

    for (int idx = tid; idx < 32 * XD_; idx += 256) {
        int c = idx / XD_, x = idx % XD_;
        float v = 0.f;
        if (c0 + c < CN_) v = Z0[(size_t)(c0 + c) * XD_ + x] + Z1[(size_t)(c0 + c) * XD_ + x];
        Zt[c][x] = v;
    }

    float acc0[12], acc1[12];
#pragma unroll
    for (int j = 0; j < 12; j++) { acc0[j] = 0.f; acc1[j] = 0.f; }

    for (int k0 = 0; k0 < XD_; k0 += 16) {
        __syncthreads();
        for (int idx = tid; idx < 16 * HD_; idx += 256) {
            int k = idx / HD_, h = idx % HD_;
            W1c[k][h] = W1[(size_t)(k0 + k) * HD_ + h];
        }
        __syncthreads();
#pragma unroll
        for (int kk = 0; kk < 16; kk++) {
            float a0 = Zt[2 * ty + 0][k0 + kk];
            float a1 = Zt[2 * ty + 1][k0 + kk];
            float4 b0 = *(const float4*)&W1c[kk][12 * tx + 0];
            float4 b1 = *(const float4*)&W1c[kk][12 * tx + 4];
            float4 b2 = *(const float4*)&W1c[kk][12 * tx + 8];
            acc0[0] += a0 * b0.x; acc0[1] += a0 * b0.y; acc0[2]  += a0 * b0.z; acc0[3]  += a0 * b0.w;
            acc0[4] += a0 * b1.x; acc0[5] += a0 * b1.y; acc0[6]  += a0 * b1.z; acc0[7]  += a0 * b1.w;
            acc0[8] += a0 * b2.x; acc0[9] += a0 * b2.y; acc0[10] += a0 * b2.z; acc0[11] += a0 * b2.w;
            acc1[0] += a1 * b0.x; acc1[1] += a1 * b0.y; acc1[2]  += a1 * b0.z; acc1[3]  += a1 * b0.w;
            acc1[4] += a1 * b1.x; acc1[5] += a1 * b1.y; acc1[6]  += a1 * b1.z; acc1[7]  += a1 * b1.w;
            acc1[8] += a1 * b2.x; acc1[9] += a1 * b2.y; acc1[10] += a1 * b2.z; acc1[11] += a1 * b2.w;
        }
    }
    int cA = c0 + 2 * ty, cB = cA + 1;
    if (cA < CN_) {
        float* o = Ysg + ((size_t)b * CN_ + cA) * HD_ + 12 * tx;
#pragma unroll
        for (int j = 0; j < 12; j++) o[j] = SCALE_ * acc0[j];
    }
    if (cB < CN_) {
        float* o = Ysg + ((size_t)b * CN_ + cB) * HD_ + 12 * tx;
#pragma unroll
        for (int j = 0; j < 12; j++) o[j] = SCALE_ * acc1[j];
    }
}

// ---------------------------------------------------------------------------
// K3: flash softmax + PV.  out[b][c][h] = softmax_u(Ys[b,c]·H[b,u]) @ H[b,:,:]
// grid (11, B), block 256. c-tile 32 (2/thread), u-tile 48 (3/thread in S,
// all in PV), h 192 (12/thread in PV).
// ---------------------------------------------------------------------------
__global__ __launch_bounds__(256) void k3_flash(const float* __restrict__ Ysg,
                                                const float* __restrict__ Hg,
                                                float* __restrict__ Outg) {
    __shared__ __align__(16) float YsL[32][200];   // [c][h], padded
    __shared__ __align__(16) float Ht[48][196];    // [u][h], padded
    __shared__ __align__(16) float Pl[32][52];     // [c][u], padded

    const int tid = threadIdx.x;
    const int tx = tid & 15;
    const int ty = tid >> 4;
    const int c0 = blockIdx.x * 32;
    const int b  = blockIdx.y;
    const int cA = 2 * ty, cB = 2 * ty + 1;

    for (int idx = tid; idx < 32 * 48; idx += 256) {
        int c = idx / 48, q = (idx % 48) * 4;
        float4 v = make_float4(0.f, 0.f, 0.f, 0.f);
        if (c0 + c < CN_) v = *(const float4*)(Ysg + ((size_t)b * CN_ + c0 + c) * HD_ + q);
        *(float4*)&YsL[c][q] = v;
    }

    float m0 = -1e30f, m1 = -1e30f, l0 = 0.f, l1 = 0.f;
    float acc0[12], acc1[12];
#pragma unroll
    for (int j = 0; j < 12; j++) { acc0[j] = 0.f; acc1[j] = 0.f; }

    for (int u0 = 0; u0 < T_; u0 += 48) {
        __syncthreads();
        for (int idx = tid; idx < 48 * 48; idx += 256) {
            int u = idx / 48, q = (idx % 48) * 4;
            float4 v = make_float4(0.f, 0.f, 0.f, 0.f);
            if (u0 + u < T_) v = *(const float4*)(Hg + ((size_t)b * T_ + u0 + u) * HD_ + q);
            *(float4*)&Ht[u][q] = v;
        }
        __syncthreads();

        // ---- GEMM1: s[2][3] = Ys[c] . Ht[u]
        float s00 = 0.f, s01 = 0.f, s02 = 0.f, s10 = 0.f, s11 = 0.f, s12 = 0.f;
        const float* ya  = &YsL[cA][0];
        const float* yb  = &YsL[cB][0];
        const float* h0p = &Ht[3 * tx + 0][0];
        const float* h1p = &Ht[3 * tx + 1][0];
        const float* h2p = &Ht[3 * tx + 2][0];
#pragma unroll 4
        for (int h = 0; h < HD_; h += 4) {
            float4 a0 = *(const float4*)(ya + h);
            float4 a1 = *(const float4*)(yb + h);
            float4 q0 = *(const float4*)(h0p + h);
            float4 q1 = *(const float4*)(h1p + h);
            float4 q2 = *(const float4*)(h2p + h);
            s00 += a0.x * q0.x + a0.y * q0.y + a0.z * q0.z + a0.w * q0.w;
            s01 += a0.x * q1.x + a0.y * q1.y + a0.z * q1.z + a0.w * q1.w;
            s02 += a0.x * q2.x + a0.y * q2.y + a0.z * q2.z + a0.w * q2.w;
            s10 += a1.x * q0.x + a1.y * q0.y + a1.z * q0.z + a1.w * q0.w;
            s11 += a1.x * q1.x + a1.y * q1.y + a1.z * q1.z + a1.w * q1.w;
            s12 += a1.x * q2.x + a1.y * q2.y + a1.z * q2.z + a1.w * q2.w;
        }
        int ub = u0 + 3 * tx;
        if (ub + 0 >= T_) { s00 = -1e30f; s10 = -1e30f; }
        if (ub + 1 >= T_) { s01 = -1e30f; s11 = -1e30f; }
        if (ub + 2 >= T_) { s02 = -1e30f; s12 = -1e30f; }

        // ---- online softmax row 0 (16 threads share a row; reduce over tx)
        {
            float tm = fmaxf(fmaxf(s00, s01), s02);
            tm = fmaxf(tm, __shfl_xor(tm, 1));
            tm = fmaxf(tm, __shfl_xor(tm, 2));
            tm = fmaxf(tm, __shfl_xor(tm, 4));
            tm = fmaxf(tm, __shfl_xor(tm, 8));
            float mn = fmaxf(m0, tm);
            float al = __expf(m0 - mn);
            float p0 = __expf(s00 - mn), p1 = __expf(s01 - mn), p2 = __expf(s02 - mn);
            Pl[cA][3 * tx + 0] = p0; Pl[cA][3 * tx + 1] = p1; Pl[cA][3 * tx + 2] = p2;
            float ts = p0 + p1 + p2;
            ts += __shfl_xor(ts, 1);
            ts += __shfl_xor(ts, 2);
            ts += __shfl_xor(ts, 4);
            ts += __shfl_xor(ts, 8);
            l0 = l0 * al + ts; m0 = mn;
#pragma unroll
            for (int j = 0; j < 12; j++) acc0[j] *= al;
        }
        // ---- online softmax row 1
        {
            float tm = fmaxf(fmaxf(s10, s11), s12);
            tm = fmaxf(tm, __shfl_xor(tm, 1));
            tm = fmaxf(tm, __shfl_xor(tm, 2));
            tm = fmaxf(tm, __shfl_xor(tm, 4));
            tm = fmaxf(tm, __shfl_xor(tm, 8));
            float mn = fmaxf(m1, tm);
            float al = __expf(m1 - mn);
            float p0 = __expf(s10 - mn), p1 = __expf(s11 - mn), p2 = __expf(s12 - mn);
            Pl[cB][3 * tx + 0] = p0; Pl[cB][3 * tx + 1] = p1; Pl[cB][3 * tx + 2] = p2;
            float ts = p0 + p1 + p2;
            ts += __shfl_xor(ts, 1);
            ts += __shfl_xor(ts, 2);
            ts += __shfl_xor(ts, 4);
            ts += __shfl_xor(ts, 8);
            l1 = l1 * al + ts; m1 = mn;
#pragma unroll
            for (int j = 0; j < 12; j++) acc1[j] *= al;
        }
        __syncthreads();

        // ---- PV: acc[c][h] += P[c][u] * Ht[u][h]
        const float* pa = &Pl[cA][0];
        const float* pb = &Pl[cB][0];
#pragma unroll 4
        for (int u = 0; u < 48; u++) {
            float p0 = pa[u], p1 = pb[u];
            const float* hr = &Ht[u][12 * tx];
            float4 v0 = *(const float4*)(hr + 0);
            float4 v1 = *(const float4*)(hr + 4);
            float4 v2 = *(const float4*)(hr + 8);
            acc0[0] += p0 * v0.x; acc0[1] += p0 * v0.y; acc0[2]  += p0 * v0.z; acc0[3]  += p0 * v0.w;
            acc0[4] += p0 * v1.x; acc0[5] += p0 * v1.y; acc0[6]  += p0 * v1.z; acc0[7]  += p0 * v1.w;
            acc0[8] += p0 * v2.x; acc0[9] += p0 * v2.y; acc0[10] += p0 * v2.z; acc0[11] += p0 * v2.w;
            acc1[0] += p1 * v0.x; acc1[1] += p1 * v0.y; acc1[2]  += p1 * v0.z; acc1[3]  += p1 * v0.w;
            acc1[4] += p1 * v1.x; acc1[5] += p1 * v1.y; acc1[6]  += p1 * v1.z; acc1[7]  += p1 * v1.w;
            acc1[8] += p1 * v2.x; acc1[9] += p1 * v2.y; acc1[10] += p1 * v2.z; acc1[11] += p1 * v2.w;
        }
    }

    // ---- epilogue
    {
        int c = c0 + cA;
        if (c < CN_) {
            float inv = 1.f / l0;
            float* o = Outg + ((size_t)b * CN_ + c) * HD_ + 12 * tx;
            *(float4*)(o + 0) = make_float4(acc0[0] * inv, acc0[1] * inv, acc0[2] * inv, acc0[3] * inv);
            *(float4*)(o + 4) = make_float4(acc0[4] * inv, acc0[5] * inv, acc0[6] * inv, acc0[7] * inv);
            *(float4*)(o + 8) = make_float4(acc0[8] * inv, acc0[9] * inv, acc0[10] * inv, acc0[11] * inv);
        }
    }
    {
        int c = c0 + cB;
        if (c < CN_) {
            float inv = 1.f / l1;
            float* o = Outg + ((size_t)b * CN_ + c) * HD_ + 12 * tx;
            *(float4*)(o + 0) = make_float4(acc1[0] * inv, acc1[1] * inv, acc1[2] * inv, acc1[3] * inv);
            *(float4*)(o + 4) = make_float4(acc1[4] * inv, acc1[5] * inv, acc1[6] * inv, acc1[7] * inv);
            *(float4*)(o + 8) = make_float4(acc1[8] * inv, acc1[9] * inv, acc1[10] * inv, acc1[11] * inv);
        }
    }
}

// ---------------------------------------------------------------------------
extern "C" void kernel_launch(void* const* d_in, const int* in_sizes, int n_in,
                              void* d_out, int out_size, void* d_ws, size_t ws_size,
                              hipStream_t stream) {
    const float* X  = (const float*)d_in[0];
    const float* H  = (const float*)d_in[1];
    const float* W1 = (const float*)d_in[2];
    const float* W2 = (const float*)d_in[3];
    float* out = (float*)d_out;

    // workspace: Zp [2][B][CN][XD] then Ys [B][CN][HD]  (~34 MB total)
    float* Zp = (float*)d_ws;
    float* Ys = Zp + (size_t)2 * B_ * CN_ * XD_;

    k1_w2x <<<dim3(6, B_, 2), 256, 0, stream>>>(X, W2, Zp);
    k2_zw1 <<<dim3(11, B_),   256, 0, stream>>>(Zp, W1, Ys);
    k3_flash<<<dim3(11, B_),  256, 0, stream>>>(Ys, H, out);
}

// Round 2
// 1068.294 us; speedup vs baseline: 1.0246x; 1.0246x over previous
//
#include <hip/hip_runtime.h>
#include <math.h>

namespace {
constexpr int B_  = 64;
constexpr int T_  = 1380;
constexpr int XD_ = 96;
constexpr int HD_ = 192;
constexpr int CN_ = 345;
constexpr float SCALE_ = 0.00736569563735987f; // 1/sqrt(96*192)
}

typedef __attribute__((ext_vector_type(8))) short bf16x8;
typedef __attribute__((ext_vector_type(4))) float f32x4;

__device__ __forceinline__ unsigned short f2bf(float f) {
    union { float f; unsigned int u; } c; c.f = f;
    unsigned int r = (c.u + 0x7fffu + ((c.u >> 16) & 1u)) >> 16;
    return (unsigned short)r;
}
__device__ __forceinline__ float bf2f(unsigned short s) {
    union { unsigned int u; float f; } c; c.u = ((unsigned int)s) << 16;
    return c.f;
}

// ---------------------------------------------------------------------------
// K1: Zp[sp][b][c][x] = sum_{t in half sp} W2[c,t] * X[b,t,x]
// grid (3, B, 2), block 256. c-tile 128 (8/thread), x-tile 96 (6/thread)
// ---------------------------------------------------------------------------
__global__ __launch_bounds__(256) void k1_w2x(const float* __restrict__ X,
                                              const float* __restrict__ W2,
                                              float* __restrict__ Zp) {
    __shared__ __align__(16) float W2t[15][132];  // [k][c], stride 132 (528B, 16B-mult)
    __shared__ __align__(16) float Xt[15][96];    // [k][x]
    const int tid = threadIdx.x;
    const int tx = tid & 15, ty = tid >> 4;
    const int c0 = blockIdx.x * 128;
    const int b  = blockIdx.y;
    const int sp = blockIdx.z;
    const int tbase = sp * (T_ / 2);

    float acc[8][6];
#pragma unroll
    for (int i = 0; i < 8; i++)
#pragma unroll
        for (int j = 0; j < 6; j++) acc[i][j] = 0.f;

    for (int k0 = 0; k0 < T_ / 2; k0 += 15) {   // 690 = 46*15
        __syncthreads();
        for (int idx = tid; idx < 128 * 15; idx += 256) {
            int c = idx / 15, k = idx % 15;
            float v = 0.f;
            if (c0 + c < CN_) v = W2[(size_t)(c0 + c) * T_ + tbase + k0 + k];
            W2t[k][c] = v;
        }
        for (int idx = tid; idx < 15 * 96; idx += 256) {
            int k = idx / 96, x = idx % 96;
            Xt[k][x] = X[((size_t)b * T_ + tbase + k0 + k) * XD_ + x];
        }
        __syncthreads();
#pragma unroll
        for (int kk = 0; kk < 15; kk++) {
            float4 a0 = *(const float4*)&W2t[kk][8 * ty];
            float4 a1 = *(const float4*)&W2t[kk][8 * ty + 4];
            float bv[6];
#pragma unroll
            for (int j = 0; j < 6; j++) bv[j] = Xt[kk][6 * tx + j];
#pragma unroll
            for (int j = 0; j < 6; j++) {
                acc[0][j] += a0.x * bv[j];
                acc[1][j] += a0.y * bv[j];
                acc[2][j] += a0.z * bv[j];
                acc[3][j] += a0.w * bv[j];
                acc[4][j] += a1.x * bv[j];
                acc[5][j] += a1.y * bv[j];
                acc[6][j] += a1.z * bv[j];
                acc[7][j] += a1.w * bv[j];
            }
        }
    }
    float* Zb = Zp + ((size_t)sp * B_ + b) * CN_ * XD_;
#pragma unroll
    for (int i = 0; i < 8; i++) {
        int c = c0 + 8 * ty + i;
        if (c < CN_) {
#pragma unroll
            for (int j = 0; j < 6; j++) Zb[(size_t)c * XD_ + 6 * tx + j] = acc[i][j];
        }
    }
}

// ---------------------------------------------------------------------------
// K2: Ys[b][c][h] = SCALE * sum_x (Zp0+Zp1)[b][c][x] * W1[x][h]
// grid (11, B), block 256.
// ---------------------------------------------------------------------------
__global__ __launch_bounds__(256) void k2_zw1(const float* __restrict__ Zp,
                                              const float* __restrict__ W1,
                                              float* __restrict__ Ysg) {
    __shared__ __align__(16) float Zt[32][100];
    __shared__ __align__(16) float W1c[16][HD_];
    const int tid = threadIdx.x;
    const int tx = tid & 15, ty = tid >> 4;
    const int c0 = blockIdx.x * 32;
    const int b  = blockIdx.y;
    const float* Z0 = Zp + (size_t)b * CN_ * XD_;
    const float* Z1 = Zp + (size_t)(B_ + b) * CN_ * XD_;

    for (int idx = tid; idx < 32 * XD_; idx += 256) {
        int c = idx / XD_, x = idx % XD_;
        float v = 0.f;
        if (c0 + c < CN_) v = Z0[(size_t)(c0 + c) * XD_ + x] + Z1[(size_t)(c0 + c) * XD_ + x];
        Zt[c][x] = v;
    }

    float acc0[12], acc1[12];
#pragma unroll
    for (int j = 0; j < 12; j++) { acc0[j] = 0.f; acc1[j] = 0.f; }

    for (int k0 = 0; k0 < XD_; k0 += 16) {
        __syncthreads();
        for (int idx = tid; idx < 16 * HD_; idx += 256) {
            int k = idx / HD_, h = idx % HD_;
            W1c[k][h] = W1[(size_t)(k0 + k) * HD_ + h];
        }
        __syncthreads();
#pragma unroll
        for (int kk = 0; kk < 16; kk++) {
            float a0 = Zt[2 * ty + 0][k0 + kk];
            float a1 = Zt[2 * ty + 1][k0 + kk];
            float4 b0 = *(const float4*)&W1c[kk][12 * tx + 0];
            float4 b1 = *(const float4*)&W1c[kk][12 * tx + 4];
            float4 b2 = *(const float4*)&W1c[kk][12 * tx + 8];
            acc0[0] += a0 * b0.x; acc0[1] += a0 * b0.y; acc0[2]  += a0 * b0.z; acc0[3]  += a0 * b0.w;
            acc0[4] += a0 * b1.x; acc0[5] += a0 * b1.y; acc0[6]  += a0 * b1.z; acc0[7]  += a0 * b1.w;
            acc0[8] += a0 * b2.x; acc0[9] += a0 * b2.y; acc0[10] += a0 * b2.z; acc0[11] += a0 * b2.w;
            acc1[0] += a1 * b0.x; acc1[1] += a1 * b0.y; acc1[2]  += a1 * b0.z; acc1[3]  += a1 * b0.w;
            acc1[4] += a1 * b1.x; acc1[5] += a1 * b1.y; acc1[6]  += a1 * b1.z; acc1[7]  += a1 * b1.w;
            acc1[8] += a1 * b2.x; acc1[9] += a1 * b2.y; acc1[10] += a1 * b2.z; acc1[11] += a1 * b2.w;
        }
    }
    int cA = c0 + 2 * ty, cB = cA + 1;
    if (cA < CN_) {
        float* o = Ysg + ((size_t)b * CN_ + cA) * HD_ + 12 * tx;
#pragma unroll
        for (int j = 0; j < 12; j++) o[j] = SCALE_ * acc0[j];
    }
    if (cB < CN_) {
        float* o = Ysg + ((size_t)b * CN_ + cB) * HD_ + 12 * tx;
#pragma unroll
        for (int j = 0; j < 12; j++) o[j] = SCALE_ * acc1[j];
    }
}

// ---------------------------------------------------------------------------
// K3: MFMA flash attention.  out[b][c][h] = softmax_u(Ys[b,c]·H[b,u]) @ H
// grid (11, B), block 256 = 4 waves.  c-tile 32 (2 m-tiles), u-tile 32
// (2 n-tiles).  Wave w: m-tile = w>>1, n-tile (u for GEMM1 / h-half for PV)
// = w&1.  Split-bf16 (hi+lo) on both Ys and H for the logit GEMM (3 MFMAs),
// plain bf16 P·H_hi for PV.
// ---------------------------------------------------------------------------
__global__ __launch_bounds__(256) void k3_mfma(const float* __restrict__ Ysg,
                                               const float* __restrict__ Hg,
                                               float* __restrict__ Outg) {
    __shared__ __align__(16) unsigned short sYsh[32][200];  // Ys hi [c][h]
    __shared__ __align__(16) unsigned short sYsl[32][200];  // Ys lo
    __shared__ __align__(16) unsigned short sHbh[32][200];  // H hi [u][h]
    __shared__ __align__(16) unsigned short sHbl[32][200];  // H lo
    __shared__ __align__(16) unsigned short sHt[192][40];   // H hi [h][u]
    __shared__ __align__(16) unsigned short sP[32][40];     // P bf16 [c][u]
    __shared__ float redM[2][2][4][4];                      // [mt][nt][quad][reg]
    __shared__ float redS[2][2][4][4];

    const int tid  = threadIdx.x;
    const int lane = tid & 63;
    const int w    = tid >> 6;
    const int tx   = lane & 15;
    const int quad = lane >> 4;
    const int mt   = w >> 1;
    const int nt   = w & 1;
    const int b    = blockIdx.y;
    const int c0   = blockIdx.x * 32;

    // ---- stage Ys tile, hi/lo split
    for (int p = tid; p < 32 * 96; p += 256) {
        int c = p / 96, hp = p % 96, h = 2 * hp;
        float2 v = make_float2(0.f, 0.f);
        if (c0 + c < CN_) v = *(const float2*)(Ysg + ((size_t)b * CN_ + c0 + c) * HD_ + h);
        unsigned short hx = f2bf(v.x), hy = f2bf(v.y);
        unsigned short lx = f2bf(v.x - bf2f(hx)), ly = f2bf(v.y - bf2f(hy));
        *(unsigned int*)&sYsh[c][h] = (unsigned int)hx | ((unsigned int)hy << 16);
        *(unsigned int*)&sYsl[c][h] = (unsigned int)lx | ((unsigned int)ly << 16);
    }

    float m_s[4], l_s[4];
    f32x4 accO[6];
#pragma unroll
    for (int r = 0; r < 4; r++) { m_s[r] = -1e30f; l_s[r] = 0.f; }
#pragma unroll
    for (int j = 0; j < 6; j++) accO[j] = (f32x4){0.f, 0.f, 0.f, 0.f};

    for (int u0 = 0; u0 < T_; u0 += 32) {   // 44 tiles, last partial
        __syncthreads();   // prev iter's reads of sHb/sHt/sP complete
        // ---- stage H tile: hi/lo [u][h] + transposed hi [h][u]
        for (int p = tid; p < 32 * 96; p += 256) {
            int u = p / 96, hp = p % 96, h = 2 * hp;
            float2 v = make_float2(0.f, 0.f);
            if (u0 + u < T_) v = *(const float2*)(Hg + ((size_t)b * T_ + u0 + u) * HD_ + h);
            unsigned short hx = f2bf(v.x), hy = f2bf(v.y);
            unsigned short lx = f2bf(v.x - bf2f(hx)), ly = f2bf(v.y - bf2f(hy));
            *(unsigned int*)&sHbh[u][h] = (unsigned int)hx | ((unsigned int)hy << 16);
            *(unsigned int*)&sHbl[u][h] = (unsigned int)lx | ((unsigned int)ly << 16);
            sHt[h][u]     = hx;
            sHt[h + 1][u] = hy;
        }
        __syncthreads();

        // ---- GEMM1: S[c][u] += Ys[c][k] * H[u][k],  K = 192
        f32x4 S0 = {0.f, 0.f, 0.f, 0.f}, S1 = {0.f, 0.f, 0.f, 0.f};
        const int ar = mt * 16 + tx;
        const int br = nt * 16 + tx;
#pragma unroll
        for (int ks = 0; ks < 6; ks++) {
            const int kc = ks * 32 + quad * 8;
            bf16x8 ah = *(const bf16x8*)&sYsh[ar][kc];
            bf16x8 al = *(const bf16x8*)&sYsl[ar][kc];
            bf16x8 bh = *(const bf16x8*)&sHbh[br][kc];
            bf16x8 bl = *(const bf16x8*)&sHbl[br][kc];
            S0 = __builtin_amdgcn_mfma_f32_16x16x32_bf16(ah, bh, S0, 0, 0, 0);
            S1 = __builtin_amdgcn_mfma_f32_16x16x32_bf16(ah, bl, S1, 0, 0, 0);
            S1 = __builtin_amdgcn_mfma_f32_16x16x32_bf16(al, bh, S1, 0, 0, 0);
        }
        // D layout: col(=u) = tx, row(=c within m-tile) = quad*4 + reg
        float sv[4];
#pragma unroll
        for (int r = 0; r < 4; r++) sv[r] = S0[r] + S1[r];
        const int uu = u0 + nt * 16 + tx;
        if (uu >= T_) {
#pragma unroll
            for (int r = 0; r < 4; r++) sv[r] = -1e30f;
        }

        // ---- online softmax over u (16 lanes here + partner wave via LDS)
        float pm[4];
#pragma unroll
        for (int r = 0; r < 4; r++) pm[r] = sv[r];
#pragma unroll
        for (int d = 1; d <= 8; d <<= 1)
#pragma unroll
            for (int r = 0; r < 4; r++) pm[r] = fmaxf(pm[r], __shfl_xor(pm[r], d));
        if (tx == 0) {
#pragma unroll
            for (int r = 0; r < 4; r++) redM[mt][nt][quad][r] = pm[r];
        }
        __syncthreads();
        float mn[4], alpha[4], p_[4];
#pragma unroll
        for (int r = 0; r < 4; r++) {
            float tm = fmaxf(pm[r], redM[mt][nt ^ 1][quad][r]);
            mn[r]    = fmaxf(m_s[r], tm);
            alpha[r] = __expf(m_s[r] - mn[r]);
            p_[r]    = __expf(sv[r] - mn[r]);
            sP[mt * 16 + quad * 4 + r][nt * 16 + tx] = f2bf(p_[r]);
        }
        float ps[4];
#pragma unroll
        for (int r = 0; r < 4; r++) ps[r] = p_[r];
#pragma unroll
        for (int d = 1; d <= 8; d <<= 1)
#pragma unroll
            for (int r = 0; r < 4; r++) ps[r] += __shfl_xor(ps[r], d);
        if (tx == 0) {
#pragma unroll
            for (int r = 0; r < 4; r++) redS[mt][nt][quad][r] = ps[r];
        }
        __syncthreads();   // covers redS + sP writes
#pragma unroll
        for (int r = 0; r < 4; r++) {
            l_s[r] = l_s[r] * alpha[r] + ps[r] + redS[mt][nt ^ 1][quad][r];
            m_s[r] = mn[r];
        }
        f32x4 alv = {alpha[0], alpha[1], alpha[2], alpha[3]};
#pragma unroll
        for (int j = 0; j < 6; j++) accO[j] *= alv;

        // ---- PV: O[c][h] += P[c][u] * H[u][h],  K = 32 (one MFMA k-step)
        bf16x8 pa = *(const bf16x8*)&sP[mt * 16 + tx][quad * 8];
#pragma unroll
        for (int j = 0; j < 6; j++) {
            const int hb0 = nt * 96 + j * 16;
            bf16x8 hb = *(const bf16x8*)&sHt[hb0 + tx][quad * 8];
            accO[j] = __builtin_amdgcn_mfma_f32_16x16x32_bf16(pa, hb, accO[j], 0, 0, 0);
        }
    }

    // ---- epilogue: D layout col(=h) = tx, row(=c) = quad*4 + reg
#pragma unroll
    for (int r = 0; r < 4; r++) {
        int c = c0 + mt * 16 + quad * 4 + r;
        if (c < CN_) {
            float inv = 1.f / l_s[r];
#pragma unroll
            for (int j = 0; j < 6; j++) {
                int h = nt * 96 + j * 16 + tx;
                Outg[((size_t)b * CN_ + c) * HD_ + h] = accO[j][r] * inv;
            }
        }
    }
}

// ---------------------------------------------------------------------------
extern "C" void kernel_launch(void* const* d_in, const int* in_sizes, int n_in,
                              void* d_out, int out_size, void* d_ws, size_t ws_size,
                              hipStream_t stream) {
    const float* X  = (const float*)d_in[0];
    const float* H  = (const float*)d_in[1];
    const float* W1 = (const float*)d_in[2];
    const float* W2 = (const float*)d_in[3];
    float* out = (float*)d_out;

    float* Zp = (float*)d_ws;                              // [2][B][CN][XD]
    float* Ys = Zp + (size_t)2 * B_ * CN_ * XD_;           // [B][CN][HD]

    k1_w2x <<<dim3(3, B_, 2), 256, 0, stream>>>(X, W2, Zp);
    k2_zw1 <<<dim3(11, B_),   256, 0, stream>>>(Zp, W1, Ys);
    k3_mfma<<<dim3(11, B_),   256, 0, stream>>>(Ys, H, out);
}

// Round 3
// 587.246 us; speedup vs baseline: 1.8638x; 1.8192x over previous
//
#include <hip/hip_runtime.h>
#include <math.h>

namespace {
constexpr int B_  = 64;
constexpr int T_  = 1380;
constexpr int XD_ = 96;
constexpr int HD_ = 192;
constexpr int CN_ = 345;
constexpr int TP_ = 1392;                      // padded T for Hth rows (16B mult)
constexpr int TH_ = 690;                       // T/2 (u-split)
constexpr float SCALE_ = 0.00736569563735987f; // 1/sqrt(96*192)
}

typedef __attribute__((ext_vector_type(8))) short bf16x8;
typedef __attribute__((ext_vector_type(4))) float f32x4;
typedef unsigned short u16;
typedef unsigned int   u32;

__device__ __forceinline__ u16 f2bf(float f) {
    union { float f; u32 u; } c; c.f = f;
    u32 r = (c.u + 0x7fffu + ((c.u >> 16) & 1u)) >> 16;
    return (u16)r;
}
__device__ __forceinline__ float bf2f(u16 s) {
    union { u32 u; float f; } c; c.u = ((u32)s) << 16;
    return c.f;
}

// ---------------------------------------------------------------------------
// K0a: split H into bf16 hi/lo, [b][u][h] layout (coalesced)
// ---------------------------------------------------------------------------
__global__ __launch_bounds__(256) void k0_split(const float* __restrict__ Hg,
                                                u16* __restrict__ Hh,
                                                u16* __restrict__ Hl) {
    const size_t n = (size_t)B_ * T_ * HD_ / 2; // float2 count
    for (size_t i = (size_t)blockIdx.x * 256 + threadIdx.x; i < n;
         i += (size_t)gridDim.x * 256) {
        float2 v = ((const float2*)Hg)[i];
        u16 hx = f2bf(v.x), hy = f2bf(v.y);
        u16 lx = f2bf(v.x - bf2f(hx)), ly = f2bf(v.y - bf2f(hy));
        ((u32*)Hh)[i] = (u32)hx | ((u32)hy << 16);
        ((u32*)Hl)[i] = (u32)lx | ((u32)ly << 16);
    }
}

// ---------------------------------------------------------------------------
// K0b: Hth[b][h][u] = bf16_hi(H[b][u][h]), row stride TP_ shorts.
// grid (22, 3, B): 64u x 64h tiles via LDS transpose.
// ---------------------------------------------------------------------------
__global__ __launch_bounds__(256) void k0_tr(const float* __restrict__ Hg,
                                             u16* __restrict__ Hth) {
    __shared__ u16 til[64][68];
    const int tid = threadIdx.x;
    const int u0 = blockIdx.x * 64, h0 = blockIdx.y * 64, b = blockIdx.z;
#pragma unroll
    for (int i = 0; i < 16; i++) {
        int lin = i * 256 + tid;
        int r = lin >> 6, c = lin & 63;
        int u = u0 + r;
        float v = (u < T_) ? Hg[((size_t)b * T_ + u) * HD_ + h0 + c] : 0.f;
        til[c][r] = f2bf(v);
    }
    __syncthreads();
#pragma unroll
    for (int i = 0; i < 4; i++) {
        int lin = i * 256 + tid;
        int hh = lin >> 4, cc = lin & 15;  // h-row, 4-u chunk
        int u = u0 + cc * 4;
        if (u + 4 <= T_) {                 // T_ % 4 == 0, exact
            ushort4 v;
            v.x = til[hh][cc * 4 + 0];
            v.y = til[hh][cc * 4 + 1];
            v.z = til[hh][cc * 4 + 2];
            v.w = til[hh][cc * 4 + 3];
            *(ushort4*)(Hth + ((size_t)b * HD_ + h0 + hh) * TP_ + u) = v;
        }
    }
}

// ---------------------------------------------------------------------------
// K1: Zp[sp][b][c][x] = sum_{t in half sp} W2[c,t] * X[b,t,x]   (round-1 ver)
// grid (6, B, 2), block 256.
// ---------------------------------------------------------------------------
__global__ __launch_bounds__(256) void k1_w2x(const float* __restrict__ X,
                                              const float* __restrict__ W2,
                                              float* __restrict__ Zp) {
    __shared__ __align__(16) float W2t[15][68];
    __shared__ __align__(16) float Xt[15][XD_];
    const int tid = threadIdx.x;
    const int tx = tid & 15, ty = tid >> 4;
    const int c0 = blockIdx.x * 64;
    const int b  = blockIdx.y;
    const int sp = blockIdx.z;
    const int tbase = sp * TH_;

    float acc[4][6];
#pragma unroll
    for (int i = 0; i < 4; i++)
#pragma unroll
        for (int j = 0; j < 6; j++) acc[i][j] = 0.f;

    for (int k0 = 0; k0 < TH_; k0 += 15) {
        __syncthreads();
        for (int idx = tid; idx < 64 * 15; idx += 256) {
            int c = idx / 15, k = idx % 15;
            float v = 0.f;
            if (c0 + c < CN_) v = W2[(size_t)(c0 + c) * T_ + tbase + k0 + k];
            W2t[k][c] = v;
        }
        for (int idx = tid; idx < 15 * XD_; idx += 256) {
            int k = idx / XD_, x = idx % XD_;
            Xt[k][x] = X[((size_t)b * T_ + tbase + k0 + k) * XD_ + x];
        }
        __syncthreads();
#pragma unroll
        for (int kk = 0; kk < 15; kk++) {
            float4 a = *(const float4*)&W2t[kk][4 * ty];
            float bv[6];
#pragma unroll
            for (int j = 0; j < 6; j++) bv[j] = Xt[kk][6 * tx + j];
#pragma unroll
            for (int j = 0; j < 6; j++) {
                acc[0][j] += a.x * bv[j];
                acc[1][j] += a.y * bv[j];
                acc[2][j] += a.z * bv[j];
                acc[3][j] += a.w * bv[j];
            }
        }
    }
    float* Zb = Zp + ((size_t)sp * B_ + b) * CN_ * XD_;
#pragma unroll
    for (int i = 0; i < 4; i++) {
        int c = c0 + 4 * ty + i;
        if (c < CN_) {
#pragma unroll
            for (int j = 0; j < 6; j++) Zb[(size_t)c * XD_ + 6 * tx + j] = acc[i][j];
        }
    }
}

// ---------------------------------------------------------------------------
// K2: Ys = SCALE * (Zp0+Zp1) @ W1, emitted as bf16 hi/lo.  grid (11, B).
// ---------------------------------------------------------------------------
__global__ __launch_bounds__(256) void k2_zw1(const float* __restrict__ Zp,
                                              const float* __restrict__ W1,
                                              u16* __restrict__ Ysh,
                                              u16* __restrict__ Ysl) {
    __shared__ __align__(16) float Zt[32][100];
    __shared__ __align__(16) float W1c[16][HD_];
    const int tid = threadIdx.x;
    const int tx = tid & 15, ty = tid >> 4;
    const int c0 = blockIdx.x * 32;
    const int b  = blockIdx.y;
    const float* Z0 = Zp + (size_t)b * CN_ * XD_;
    const float* Z1 = Zp + (size_t)(B_ + b) * CN_ * XD_;

    for (int idx = tid; idx < 32 * XD_; idx += 256) {
        int c = idx / XD_, x = idx % XD_;
        float v = 0.f;
        if (c0 + c < CN_) v = Z0[(size_t)(c0 + c) * XD_ + x] + Z1[(size_t)(c0 + c) * XD_ + x];
        Zt[c][x] = v;
    }

    float acc0[12], acc1[12];
#pragma unroll
    for (int j = 0; j < 12; j++) { acc0[j] = 0.f; acc1[j] = 0.f; }

    for (int k0 = 0; k0 < XD_; k0 += 16) {
        __syncthreads();
        for (int idx = tid; idx < 16 * HD_; idx += 256) {
            int k = idx / HD_, h = idx % HD_;
            W1c[k][h] = W1[(size_t)(k0 + k) * HD_ + h];
        }
        __syncthreads();
#pragma unroll
        for (int kk = 0; kk < 16; kk++) {
            float a0 = Zt[2 * ty + 0][k0 + kk];
            float a1 = Zt[2 * ty + 1][k0 + kk];
            float4 b0 = *(const float4*)&W1c[kk][12 * tx + 0];
            float4 b1 = *(const float4*)&W1c[kk][12 * tx + 4];
            float4 b2 = *(const float4*)&W1c[kk][12 * tx + 8];
            acc0[0] += a0 * b0.x; acc0[1] += a0 * b0.y; acc0[2]  += a0 * b0.z; acc0[3]  += a0 * b0.w;
            acc0[4] += a0 * b1.x; acc0[5] += a0 * b1.y; acc0[6]  += a0 * b1.z; acc0[7]  += a0 * b1.w;
            acc0[8] += a0 * b2.x; acc0[9] += a0 * b2.y; acc0[10] += a0 * b2.z; acc0[11] += a0 * b2.w;
            acc1[0] += a1 * b0.x; acc1[1] += a1 * b0.y; acc1[2]  += a1 * b0.z; acc1[3]  += a1 * b0.w;
            acc1[4] += a1 * b1.x; acc1[5] += a1 * b1.y; acc1[6]  += a1 * b1.z; acc1[7]  += a1 * b1.w;
            acc1[8] += a1 * b2.x; acc1[9] += a1 * b2.y; acc1[10] += a1 * b2.z; acc1[11] += a1 * b2.w;
        }
    }
#pragma unroll
    for (int rr = 0; rr < 2; rr++) {
        int c = c0 + 2 * ty + rr;
        if (c < CN_) {
            float* accp = rr ? acc1 : acc0;
            size_t base = ((size_t)b * CN_ + c) * HD_ + 12 * tx;
#pragma unroll
            for (int j = 0; j < 12; j++) {
                float y = SCALE_ * accp[j];
                u16 hi = f2bf(y);
                u16 lo = f2bf(y - bf2f(hi));
                Ysh[base + j] = hi;
                Ysl[base + j] = lo;
            }
        }
    }
}

// ---------------------------------------------------------------------------
// K3: MFMA flash attention over a u-half.  grid (6, B, 2), block 256 = 4 waves.
// c-tile 64: wave w owns c-rows [c0+16w, c0+16w+16) x full u-tile 32 ->
// softmax entirely within-wave.  A-frags (Ys hi/lo) in registers, loop-invariant.
// Writes unnormalized O + per-row (m,l) partials; k_merge combines halves.
// ---------------------------------------------------------------------------
__global__ __launch_bounds__(256, 3) void k3_mfma(const u16* __restrict__ Ysh,
                                                  const u16* __restrict__ Ysl,
                                                  const u16* __restrict__ Hh,
                                                  const u16* __restrict__ Hl,
                                                  const u16* __restrict__ Hth,
                                                  float* __restrict__ Op,
                                                  float* __restrict__ Ml,
                                                  float* __restrict__ Ll) {
    __shared__ __align__(16) u16 sHh[32][200];   // [u][h] hi (25 chunks/row -> conflict-free)
    __shared__ __align__(16) u16 sHl[32][200];   // [u][h] lo
    __shared__ __align__(16) u16 sHt[192][40];   // [h][u] hi (5 chunks/row)
    __shared__ __align__(16) u16 sP[64][40];     // [c][u] bf16

    const int tid  = threadIdx.x;
    const int lane = tid & 63;
    const int w    = tid >> 6;
    const int tx   = lane & 15;
    const int quad = lane >> 4;
    const int b    = blockIdx.y;
    const int c0   = blockIdx.x * 64;
    const int sp   = blockIdx.z;
    const int us   = sp * TH_, ue = us + TH_;

    // ---- loop-invariant A-fragments (Ys hi/lo) into registers
    bf16x8 Ah[6], Al[6];
    const int ar = c0 + w * 16 + tx;
    if (ar < CN_) {
        const u16* yh = Ysh + ((size_t)b * CN_ + ar) * HD_;
        const u16* yl = Ysl + ((size_t)b * CN_ + ar) * HD_;
#pragma unroll
        for (int ks = 0; ks < 6; ks++) {
            Ah[ks] = *(const bf16x8*)(yh + ks * 32 + quad * 8);
            Al[ks] = *(const bf16x8*)(yl + ks * 32 + quad * 8);
        }
    } else {
#pragma unroll
        for (int ks = 0; ks < 6; ks++) { Ah[ks] = (bf16x8)0; Al[ks] = (bf16x8)0; }
    }

    float m_s[4], l_s[4];
    f32x4 accO[12];
#pragma unroll
    for (int r = 0; r < 4; r++) { m_s[r] = -1e30f; l_s[r] = 0.f; }
#pragma unroll
    for (int j = 0; j < 12; j++) accO[j] = (f32x4){0.f, 0.f, 0.f, 0.f};

    const u16* srch = Hh + (size_t)b * T_ * HD_;
    const u16* srcl = Hl + (size_t)b * T_ * HD_;
    const u16* srct = Hth + (size_t)b * HD_ * TP_;

    for (int t = 0; t < 22; t++) {           // 22*32 >= 690
        const int u0 = us + t * 32;
        __syncthreads();
        // ---- stage sHh/sHl: 768 16B-chunks each, coalesced, conflict-free
#pragma unroll
        for (int i = 0; i < 3; i++) {
            int cid = tid + i * 256;
            int u = cid / 24, c = cid % 24;
            uint4 vh = {0, 0, 0, 0}, vl = {0, 0, 0, 0};
            if (u0 + u < ue) {
                vh = *(const uint4*)(srch + ((size_t)(u0 + u)) * HD_ + c * 8);
                vl = *(const uint4*)(srcl + ((size_t)(u0 + u)) * HD_ + c * 8);
            }
            *(uint4*)&sHh[u][c * 8] = vh;
            *(uint4*)&sHl[u][c * 8] = vl;
        }
        // ---- stage sHt: 768 16B-chunks (8-u runs from padded Hth rows)
#pragma unroll
        for (int i = 0; i < 3; i++) {
            int cid = tid + i * 256;
            int h = cid >> 2, cc = cid & 3;
            int ub = u0 + cc * 8;
            uint4 v = {0, 0, 0, 0};
            if (ub + 8 <= ue) {
                v = *(const uint4*)(srct + (size_t)h * TP_ + ub);
            } else if (ub < ue) {
                const u16* p = srct + (size_t)h * TP_;
                u32 w0 = 0, w1 = 0, w2 = 0, w3 = 0;
                if (ub + 0 < ue) w0 |= (u32)p[ub + 0];
                if (ub + 1 < ue) w0 |= (u32)p[ub + 1] << 16;
                if (ub + 2 < ue) w1 |= (u32)p[ub + 2];
                if (ub + 3 < ue) w1 |= (u32)p[ub + 3] << 16;
                if (ub + 4 < ue) w2 |= (u32)p[ub + 4];
                if (ub + 5 < ue) w2 |= (u32)p[ub + 5] << 16;
                if (ub + 6 < ue) w3 |= (u32)p[ub + 6];
                if (ub + 7 < ue) w3 |= (u32)p[ub + 7] << 16;
                v = make_uint4(w0, w1, w2, w3);
            }
            *(uint4*)&sHt[h][cc * 8] = v;
        }
        __syncthreads();

        // ---- GEMM1: S[c][u], K=192, split-bf16 (hi*hi + hi*lo + lo*hi)
        f32x4 s0a = {0.f, 0.f, 0.f, 0.f}, s1a = {0.f, 0.f, 0.f, 0.f};
        f32x4 s0b = {0.f, 0.f, 0.f, 0.f}, s1b = {0.f, 0.f, 0.f, 0.f};
#pragma unroll
        for (int ks = 0; ks < 6; ks++) {
            const int kc = ks * 32 + quad * 8;
            bf16x8 bh0 = *(const bf16x8*)&sHh[tx][kc];
            bf16x8 bl0 = *(const bf16x8*)&sHl[tx][kc];
            bf16x8 bh1 = *(const bf16x8*)&sHh[16 + tx][kc];
            bf16x8 bl1 = *(const bf16x8*)&sHl[16 + tx][kc];
            s0a = __builtin_amdgcn_mfma_f32_16x16x32_bf16(Ah[ks], bh0, s0a, 0, 0, 0);
            s1a = __builtin_amdgcn_mfma_f32_16x16x32_bf16(Ah[ks], bl0, s1a, 0, 0, 0);
            s1a = __builtin_amdgcn_mfma_f32_16x16x32_bf16(Al[ks], bh0, s1a, 0, 0, 0);
            s0b = __builtin_amdgcn_mfma_f32_16x16x32_bf16(Ah[ks], bh1, s0b, 0, 0, 0);
            s1b = __builtin_amdgcn_mfma_f32_16x16x32_bf16(Ah[ks], bl1, s1b, 0, 0, 0);
            s1b = __builtin_amdgcn_mfma_f32_16x16x32_bf16(Al[ks], bh1, s1b, 0, 0, 0);
        }
        float sv0[4], sv1[4];
        const bool okA = (u0 + tx) < ue, okB = (u0 + 16 + tx) < ue;
#pragma unroll
        for (int r = 0; r < 4; r++) {
            sv0[r] = okA ? (s0a[r] + s1a[r]) : -1e30f;
            sv1[r] = okB ? (s0b[r] + s1b[r]) : -1e30f;
        }

        // ---- online softmax, fully within-wave (16-lane groups)
        float alpha[4];
#pragma unroll
        for (int r = 0; r < 4; r++) {
            float mx = fmaxf(sv0[r], sv1[r]);
            mx = fmaxf(mx, __shfl_xor(mx, 1));
            mx = fmaxf(mx, __shfl_xor(mx, 2));
            mx = fmaxf(mx, __shfl_xor(mx, 4));
            mx = fmaxf(mx, __shfl_xor(mx, 8));
            float mn = fmaxf(m_s[r], mx);
            alpha[r] = __expf(m_s[r] - mn);
            float p0 = __expf(sv0[r] - mn);
            float p1 = __expf(sv1[r] - mn);
            sP[w * 16 + quad * 4 + r][tx]      = f2bf(p0);
            sP[w * 16 + quad * 4 + r][16 + tx] = f2bf(p1);
            float s = p0 + p1;
            s += __shfl_xor(s, 1);
            s += __shfl_xor(s, 2);
            s += __shfl_xor(s, 4);
            s += __shfl_xor(s, 8);
            l_s[r] = l_s[r] * alpha[r] + s;
            m_s[r] = mn;
        }
        f32x4 alv = {alpha[0], alpha[1], alpha[2], alpha[3]};
#pragma unroll
        for (int j = 0; j < 12; j++) accO[j] *= alv;
        __syncthreads();   // sP visible (also keeps waves tile-aligned)

        // ---- PV: O += P * H, K=32 (one MFMA k-step), hi-H only
        bf16x8 pa = *(const bf16x8*)&sP[w * 16 + tx][quad * 8];
#pragma unroll
        for (int j = 0; j < 12; j++) {
            bf16x8 hb = *(const bf16x8*)&sHt[j * 16 + tx][quad * 8];
            accO[j] = __builtin_amdgcn_mfma_f32_16x16x32_bf16(pa, hb, accO[j], 0, 0, 0);
        }
    }

    // ---- epilogue: unnormalized partials + (m,l)
#pragma unroll
    for (int r = 0; r < 4; r++) {
        int c = c0 + w * 16 + quad * 4 + r;
        if (c < CN_) {
            float* orow = Op + (((size_t)sp * B_ + b) * CN_ + c) * HD_;
#pragma unroll
            for (int j = 0; j < 12; j++) orow[j * 16 + tx] = accO[j][r];
            if (tx == 0) {
                size_t mi = ((size_t)sp * B_ + b) * CN_ + c;
                Ml[mi] = m_s[r];
                Ll[mi] = l_s[r];
            }
        }
    }
}

// ---------------------------------------------------------------------------
// K4: merge the two u-half partials.  grid (CN, B), block 192.
// ---------------------------------------------------------------------------
__global__ __launch_bounds__(192) void k_merge(const float* __restrict__ Op,
                                               const float* __restrict__ Ml,
                                               const float* __restrict__ Ll,
                                               float* __restrict__ out) {
    const int c = blockIdx.x, b = blockIdx.y, h = threadIdx.x;
    const size_t i0 = (size_t)b * CN_ + c;
    const size_t i1 = (size_t)B_ * CN_ + i0;
    float m0 = Ml[i0], m1 = Ml[i1];
    float l0 = Ll[i0], l1 = Ll[i1];
    float M  = fmaxf(m0, m1);
    float e0 = __expf(m0 - M), e1 = __expf(m1 - M);
    float L  = l0 * e0 + l1 * e1;
    float o0 = Op[i0 * HD_ + h], o1 = Op[i1 * HD_ + h];
    out[i0 * HD_ + h] = (o0 * e0 + o1 * e1) / L;
}

// ---------------------------------------------------------------------------
extern "C" void kernel_launch(void* const* d_in, const int* in_sizes, int n_in,
                              void* d_out, int out_size, void* d_ws, size_t ws_size,
                              hipStream_t stream) {
    const float* X  = (const float*)d_in[0];
    const float* H  = (const float*)d_in[1];
    const float* W1 = (const float*)d_in[2];
    const float* W2 = (const float*)d_in[3];
    float* out = (float*)d_out;

    char* ws = (char*)d_ws;
    float* Zp  = (float*)(ws);                       // 16,957,440 B
    u16*   Ysh = (u16*)(ws + 16957440);              //  8,478,720 B
    u16*   Ysl = (u16*)(ws + 25436160);              //  8,478,720 B
    u16*   Hh  = (u16*)(ws + 33914880);              // 33,914,880 B
    u16*   Hl  = (u16*)(ws + 67829760);              // 33,914,880 B
    u16*   Hth = (u16*)(ws + 101744640);             // 34,209,792 B (stride TP_)
    float* Op  = (float*)(ws + 135954432);           // 33,914,880 B
    float* Ml  = (float*)(ws + 169869312);           //    176,640 B
    float* Ll  = (float*)(ws + 170045952);           //    176,640 B  (end ~170.2 MB)

    k0_split<<<dim3(1024),        256, 0, stream>>>(H, Hh, Hl);
    k0_tr   <<<dim3(22, 3, B_),   256, 0, stream>>>(H, Hth);
    k1_w2x  <<<dim3(6, B_, 2),    256, 0, stream>>>(X, W2, Zp);
    k2_zw1  <<<dim3(11, B_),      256, 0, stream>>>(Zp, W1, Ysh, Ysl);
    k3_mfma <<<dim3(6, B_, 2),    256, 0, stream>>>(Ysh, Ysl, Hh, Hl, Hth, Op, Ml, Ll);
    k_merge <<<dim3(CN_, B_),     192, 0, stream>>>(Op, Ml, Ll, out);
}

// Round 4
// 532.949 us; speedup vs baseline: 2.0537x; 1.1019x over previous
//
#include <hip/hip_runtime.h>
#include <math.h>

namespace {
constexpr int B_  = 64;
constexpr int T_  = 1380;
constexpr int XD_ = 96;
constexpr int HD_ = 192;
constexpr int CN_ = 345;
constexpr int CP_ = 384;                       // padded CN for W2h rows
constexpr int TP_ = 1392;                      // padded T for Hth rows (16B mult)
constexpr int TP2_ = 1408;                     // padded T for k12 K-dim (22*64)
constexpr int TH_ = 690;                       // T/2 (u-split in k3)
constexpr float SCALE_ = 0.00736569563735987f; // 1/sqrt(96*192)
}

typedef __attribute__((ext_vector_type(8))) short bf16x8;
typedef __attribute__((ext_vector_type(4))) float f32x4;
typedef unsigned short u16;
typedef unsigned int   u32;

__device__ __forceinline__ u16 f2bf(float f) {
    union { float f; u32 u; } c; c.f = f;
    u32 r = (c.u + 0x7fffu + ((c.u >> 16) & 1u)) >> 16;
    return (u16)r;
}
__device__ __forceinline__ float bf2f(u16 s) {
    union { u32 u; float f; } c; c.u = ((u32)s) << 16;
    return c.f;
}

// ---------------------------------------------------------------------------
// K0a: split H into bf16 hi/lo, [b][u][h] layout (coalesced)
// ---------------------------------------------------------------------------
__global__ __launch_bounds__(256) void k0_split(const float* __restrict__ Hg,
                                                u16* __restrict__ Hh,
                                                u16* __restrict__ Hl) {
    const size_t n = (size_t)B_ * T_ * HD_ / 2;
    for (size_t i = (size_t)blockIdx.x * 256 + threadIdx.x; i < n;
         i += (size_t)gridDim.x * 256) {
        float2 v = ((const float2*)Hg)[i];
        u16 hx = f2bf(v.x), hy = f2bf(v.y);
        u16 lx = f2bf(v.x - bf2f(hx)), ly = f2bf(v.y - bf2f(hy));
        ((u32*)Hh)[i] = (u32)hx | ((u32)hy << 16);
        ((u32*)Hl)[i] = (u32)lx | ((u32)ly << 16);
    }
}

// ---------------------------------------------------------------------------
// K0b: Hth[b][h][u] = bf16_hi(H[b][u][h]), row stride TP_ shorts.
// ---------------------------------------------------------------------------
__global__ __launch_bounds__(256) void k0_tr(const float* __restrict__ Hg,
                                             u16* __restrict__ Hth) {
    __shared__ u16 til[64][68];
    const int tid = threadIdx.x;
    const int u0 = blockIdx.x * 64, h0 = blockIdx.y * 64, b = blockIdx.z;
#pragma unroll
    for (int i = 0; i < 16; i++) {
        int lin = i * 256 + tid;
        int r = lin >> 6, c = lin & 63;
        int u = u0 + r;
        float v = (u < T_) ? Hg[((size_t)b * T_ + u) * HD_ + h0 + c] : 0.f;
        til[c][r] = f2bf(v);
    }
    __syncthreads();
#pragma unroll
    for (int i = 0; i < 4; i++) {
        int lin = i * 256 + tid;
        int hh = lin >> 4, cc = lin & 15;
        int u = u0 + cc * 4;
        if (u + 4 <= T_) {
            ushort4 v;
            v.x = til[hh][cc * 4 + 0];
            v.y = til[hh][cc * 4 + 1];
            v.z = til[hh][cc * 4 + 2];
            v.w = til[hh][cc * 4 + 3];
            *(ushort4*)(Hth + ((size_t)b * HD_ + h0 + hh) * TP_ + u) = v;
        }
    }
}

// ---------------------------------------------------------------------------
// K0c: X -> Xth/Xtl [b][x][t] bf16 hi/lo, t padded to TP2_ with zeros.
// grid (22, B): t-tile 64, full x=96.
// ---------------------------------------------------------------------------
__global__ __launch_bounds__(256) void k0_x(const float* __restrict__ Xg,
                                            u16* __restrict__ Xth,
                                            u16* __restrict__ Xtl) {
    __shared__ __align__(16) u16 tih[96][72];
    __shared__ __align__(16) u16 til[96][72];
    const int tid = threadIdx.x;
    const int t0 = blockIdx.x * 64, b = blockIdx.y;
#pragma unroll
    for (int i = 0; i < 24; i++) {
        int lin = i * 256 + tid;           // 0..6143
        int r = lin / 96, x = lin % 96;
        float v = (t0 + r < T_) ? Xg[((size_t)b * T_ + t0 + r) * XD_ + x] : 0.f;
        u16 hi = f2bf(v);
        tih[x][r] = hi;
        til[x][r] = f2bf(v - bf2f(hi));
    }
    __syncthreads();
#pragma unroll
    for (int i = 0; i < 6; i++) {
        int id = i * 256 + tid;            // 0..1535
        int buf = (id >= 768);
        int cid = buf ? id - 768 : id;
        int x = cid >> 3, col = cid & 7;
        uint4 v = *(const uint4*)&(buf ? til : tih)[x][col * 8];
        u16* dst = (buf ? Xtl : Xth) + ((size_t)b * XD_ + x) * TP2_ + t0 + col * 8;
        *(uint4*)dst = v;
    }
}

// ---------------------------------------------------------------------------
// K0d: W2 -> W2h/W2l [CP_][TP2_] bf16 hi/lo, zero padded both dims.
// ---------------------------------------------------------------------------
__global__ __launch_bounds__(256) void k0_w2(const float* __restrict__ W2g,
                                             u16* __restrict__ W2h,
                                             u16* __restrict__ W2l) {
    const int n = CP_ * (TP2_ / 2);        // u32 elements
    for (int i = blockIdx.x * 256 + threadIdx.x; i < n; i += gridDim.x * 256) {
        int c = i / (TP2_ / 2), tc = i % (TP2_ / 2);
        int t = tc * 2;
        float v0 = 0.f, v1 = 0.f;
        if (c < CN_) {
            if (t < T_)     v0 = W2g[(size_t)c * T_ + t];
            if (t + 1 < T_) v1 = W2g[(size_t)c * T_ + t + 1];
        }
        u16 h0 = f2bf(v0), h1 = f2bf(v1);
        u16 l0 = f2bf(v0 - bf2f(h0)), l1 = f2bf(v1 - bf2f(h1));
        ((u32*)W2h)[i] = (u32)h0 | ((u32)h1 << 16);
        ((u32*)W2l)[i] = (u32)l0 | ((u32)l1 << 16);
    }
}

// ---------------------------------------------------------------------------
// K0e: W1 [x][h] -> W1th/W1tl [h][x] bf16 hi/lo (tiny).
// ---------------------------------------------------------------------------
__global__ __launch_bounds__(256) void k0_w1(const float* __restrict__ W1g,
                                             u16* __restrict__ W1th,
                                             u16* __restrict__ W1tl) {
    int i = blockIdx.x * 256 + threadIdx.x;   // 0..18431
    if (i < HD_ * XD_) {
        int h = i / XD_, x = i % XD_;
        float v = W1g[(size_t)x * HD_ + h];
        u16 hi = f2bf(v);
        W1th[i] = hi;
        W1tl[i] = f2bf(v - bf2f(hi));
    }
}

// ---------------------------------------------------------------------------
// K12: fused MFMA GEMM.  Phase 1: Z[c,x] = W2@X[b] (split-bf16, K=1408).
// Phase 2: Y = SCALE * Z @ W1 (split-bf16, B-frags straight from global),
// emitted as Ysh/Ysl.  grid (6, B), block 256 = 4 waves, c-tile 64.
// ---------------------------------------------------------------------------
__global__ __launch_bounds__(256) void k12_mfma(const u16* __restrict__ W2h,
                                                const u16* __restrict__ W2l,
                                                const u16* __restrict__ Xth,
                                                const u16* __restrict__ Xtl,
                                                const u16* __restrict__ W1th,
                                                const u16* __restrict__ W1tl,
                                                u16* __restrict__ Ysh,
                                                u16* __restrict__ Ysl) {
    __shared__ __align__(16) char smem[46080];
    u16* sAh = (u16*)smem;                  // 64 x 72
    u16* sAl = (u16*)(smem + 9216);
    u16* sBh = (u16*)(smem + 18432);        // 96 x 72
    u16* sBl = (u16*)(smem + 32256);
    float* sZ = (float*)smem;               // phase 2: 64 x 100 fp32

    const int tid  = threadIdx.x;
    const int lane = tid & 63;
    const int w    = tid >> 6;
    const int tx   = lane & 15;
    const int quad = lane >> 4;
    const int b    = blockIdx.y;
    const int c0   = blockIdx.x * 64;

    f32x4 accZ[6];
#pragma unroll
    for (int j = 0; j < 6; j++) accZ[j] = (f32x4){0.f, 0.f, 0.f, 0.f};

    uint4 pf[10];
    // ---- prefetch step 0
    {
        const int k0 = 0;
#pragma unroll
        for (int i = 0; i < 4; i++) {
            int id = tid + i * 256;
            int buf = id >> 9, cid = id & 511;
            int row = cid >> 3, col = cid & 7;
            pf[i] = *(const uint4*)((buf ? W2l : W2h) + (size_t)(c0 + row) * TP2_ + k0 + col * 8);
        }
#pragma unroll
        for (int i = 0; i < 6; i++) {
            int id = tid + i * 256;
            int buf = (id >= 768) ? 1 : 0;
            int cid = id - buf * 768;
            int row = cid >> 3, col = cid & 7;
            pf[4 + i] = *(const uint4*)((buf ? Xtl : Xth) + ((size_t)b * XD_ + row) * TP2_ + k0 + col * 8);
        }
    }

    for (int s = 0; s < 22; s++) {
        __syncthreads();
        // ---- commit prefetched tile to LDS
#pragma unroll
        for (int i = 0; i < 4; i++) {
            int id = tid + i * 256;
            int buf = id >> 9, cid = id & 511;
            int row = cid >> 3, col = cid & 7;
            *(uint4*)((buf ? sAl : sAh) + row * 72 + col * 8) = pf[i];
        }
#pragma unroll
        for (int i = 0; i < 6; i++) {
            int id = tid + i * 256;
            int buf = (id >= 768) ? 1 : 0;
            int cid = id - buf * 768;
            int row = cid >> 3, col = cid & 7;
            *(uint4*)((buf ? sBl : sBh) + row * 72 + col * 8) = pf[4 + i];
        }
        // ---- prefetch next tile
        if (s < 21) {
            const int k0 = (s + 1) * 64;
#pragma unroll
            for (int i = 0; i < 4; i++) {
                int id = tid + i * 256;
                int buf = id >> 9, cid = id & 511;
                int row = cid >> 3, col = cid & 7;
                pf[i] = *(const uint4*)((buf ? W2l : W2h) + (size_t)(c0 + row) * TP2_ + k0 + col * 8);
            }
#pragma unroll
            for (int i = 0; i < 6; i++) {
                int id = tid + i * 256;
                int buf = (id >= 768) ? 1 : 0;
                int cid = id - buf * 768;
                int row = cid >> 3, col = cid & 7;
                pf[4 + i] = *(const uint4*)((buf ? Xtl : Xth) + ((size_t)b * XD_ + row) * TP2_ + k0 + col * 8);
            }
        }
        __syncthreads();
        // ---- compute: 2 x k32 sub-steps, 6 n-tiles, 3 split terms
#pragma unroll
        for (int sub = 0; sub < 2; sub++) {
            const int kc = sub * 32 + quad * 8;
            bf16x8 ah = *(const bf16x8*)(sAh + (w * 16 + tx) * 72 + kc);
            bf16x8 al = *(const bf16x8*)(sAl + (w * 16 + tx) * 72 + kc);
#pragma unroll
            for (int nt = 0; nt < 6; nt++) {
                bf16x8 bh = *(const bf16x8*)(sBh + (nt * 16 + tx) * 72 + kc);
                bf16x8 bl = *(const bf16x8*)(sBl + (nt * 16 + tx) * 72 + kc);
                accZ[nt] = __builtin_amdgcn_mfma_f32_16x16x32_bf16(ah, bh, accZ[nt], 0, 0, 0);
                accZ[nt] = __builtin_amdgcn_mfma_f32_16x16x32_bf16(ah, bl, accZ[nt], 0, 0, 0);
                accZ[nt] = __builtin_amdgcn_mfma_f32_16x16x32_bf16(al, bh, accZ[nt], 0, 0, 0);
            }
        }
    }

    // ---- phase 2: Y = SCALE * Z @ W1
    __syncthreads();
#pragma unroll
    for (int nt = 0; nt < 6; nt++)
#pragma unroll
        for (int r = 0; r < 4; r++)
            sZ[(w * 16 + quad * 4 + r) * 100 + nt * 16 + tx] = accZ[nt][r];
    __syncthreads();

    bf16x8 A2h[3], A2l[3];
#pragma unroll
    for (int ks = 0; ks < 3; ks++) {
        const float* zrow = sZ + (w * 16 + tx) * 100 + ks * 32 + quad * 8;
        bf16x8 vh, vl;
#pragma unroll
        for (int j = 0; j < 8; j++) {
            float v = zrow[j];
            u16 hi = f2bf(v);
            vh[j] = (short)hi;
            vl[j] = (short)f2bf(v - bf2f(hi));
        }
        A2h[ks] = vh; A2l[ks] = vl;
    }

    f32x4 accY[12];
#pragma unroll
    for (int j = 0; j < 12; j++) accY[j] = (f32x4){0.f, 0.f, 0.f, 0.f};
#pragma unroll
    for (int nt = 0; nt < 12; nt++) {
        const int hrow = nt * 16 + tx;
#pragma unroll
        for (int ks = 0; ks < 3; ks++) {
            bf16x8 bh = *(const bf16x8*)(W1th + (size_t)hrow * XD_ + ks * 32 + quad * 8);
            bf16x8 bl = *(const bf16x8*)(W1tl + (size_t)hrow * XD_ + ks * 32 + quad * 8);
            accY[nt] = __builtin_amdgcn_mfma_f32_16x16x32_bf16(A2h[ks], bh, accY[nt], 0, 0, 0);
            accY[nt] = __builtin_amdgcn_mfma_f32_16x16x32_bf16(A2h[ks], bl, accY[nt], 0, 0, 0);
            accY[nt] = __builtin_amdgcn_mfma_f32_16x16x32_bf16(A2l[ks], bh, accY[nt], 0, 0, 0);
        }
    }

#pragma unroll
    for (int r = 0; r < 4; r++) {
        int c = c0 + w * 16 + quad * 4 + r;
        if (c < CN_) {
            size_t base = ((size_t)b * CN_ + c) * HD_;
#pragma unroll
            for (int nt = 0; nt < 12; nt++) {
                float y = SCALE_ * accY[nt][r];
                u16 hi = f2bf(y);
                Ysh[base + nt * 16 + tx] = hi;
                Ysl[base + nt * 16 + tx] = f2bf(y - bf2f(hi));
            }
        }
    }
}

// ---------------------------------------------------------------------------
// K3: MFMA flash attention over a u-half.  grid (6, B, 2), block 256 = 4 waves.
// ---------------------------------------------------------------------------
__global__ __launch_bounds__(256, 3) void k3_mfma(const u16* __restrict__ Ysh,
                                                  const u16* __restrict__ Ysl,
                                                  const u16* __restrict__ Hh,
                                                  const u16* __restrict__ Hl,
                                                  const u16* __restrict__ Hth,
                                                  float* __restrict__ Op,
                                                  float* __restrict__ Ml,
                                                  float* __restrict__ Ll) {
    __shared__ __align__(16) u16 sHh[32][200];
    __shared__ __align__(16) u16 sHl[32][200];
    __shared__ __align__(16) u16 sHt[192][40];
    __shared__ __align__(16) u16 sP[64][40];

    const int tid  = threadIdx.x;
    const int lane = tid & 63;
    const int w    = tid >> 6;
    const int tx   = lane & 15;
    const int quad = lane >> 4;
    const int b    = blockIdx.y;
    const int c0   = blockIdx.x * 64;
    const int sp   = blockIdx.z;
    const int us   = sp * TH_, ue = us + TH_;

    bf16x8 Ah[6], Al[6];
    const int ar = c0 + w * 16 + tx;
    if (ar < CN_) {
        const u16* yh = Ysh + ((size_t)b * CN_ + ar) * HD_;
        const u16* yl = Ysl + ((size_t)b * CN_ + ar) * HD_;
#pragma unroll
        for (int ks = 0; ks < 6; ks++) {
            Ah[ks] = *(const bf16x8*)(yh + ks * 32 + quad * 8);
            Al[ks] = *(const bf16x8*)(yl + ks * 32 + quad * 8);
        }
    } else {
#pragma unroll
        for (int ks = 0; ks < 6; ks++) { Ah[ks] = (bf16x8)0; Al[ks] = (bf16x8)0; }
    }

    float m_s[4], l_s[4];
    f32x4 accO[12];
#pragma unroll
    for (int r = 0; r < 4; r++) { m_s[r] = -1e30f; l_s[r] = 0.f; }
#pragma unroll
    for (int j = 0; j < 12; j++) accO[j] = (f32x4){0.f, 0.f, 0.f, 0.f};

    const u16* srch = Hh + (size_t)b * T_ * HD_;
    const u16* srcl = Hl + (size_t)b * T_ * HD_;
    const u16* srct = Hth + (size_t)b * HD_ * TP_;

    for (int t = 0; t < 22; t++) {
        const int u0 = us + t * 32;
        __syncthreads();
#pragma unroll
        for (int i = 0; i < 3; i++) {
            int cid = tid + i * 256;
            int u = cid / 24, c = cid % 24;
            uint4 vh = {0, 0, 0, 0}, vl = {0, 0, 0, 0};
            if (u0 + u < ue) {
                vh = *(const uint4*)(srch + ((size_t)(u0 + u)) * HD_ + c * 8);
                vl = *(const uint4*)(srcl + ((size_t)(u0 + u)) * HD_ + c * 8);
            }
            *(uint4*)&sHh[u][c * 8] = vh;
            *(uint4*)&sHl[u][c * 8] = vl;
        }
#pragma unroll
        for (int i = 0; i < 3; i++) {
            int cid = tid + i * 256;
            int h = cid >> 2, cc = cid & 3;
            int ub = u0 + cc * 8;
            uint4 v = {0, 0, 0, 0};
            if (ub + 8 <= ue) {
                v = *(const uint4*)(srct + (size_t)h * TP_ + ub);
            } else if (ub < ue) {
                const u16* p = srct + (size_t)h * TP_;
                u32 w0 = 0, w1 = 0, w2 = 0, w3 = 0;
                if (ub + 0 < ue) w0 |= (u32)p[ub + 0];
                if (ub + 1 < ue) w0 |= (u32)p[ub + 1] << 16;
                if (ub + 2 < ue) w1 |= (u32)p[ub + 2];
                if (ub + 3 < ue) w1 |= (u32)p[ub + 3] << 16;
                if (ub + 4 < ue) w2 |= (u32)p[ub + 4];
                if (ub + 5 < ue) w2 |= (u32)p[ub + 5] << 16;
                if (ub + 6 < ue) w3 |= (u32)p[ub + 6];
                if (ub + 7 < ue) w3 |= (u32)p[ub + 7] << 16;
                v = make_uint4(w0, w1, w2, w3);
            }
            *(uint4*)&sHt[h][cc * 8] = v;
        }
        __syncthreads();

        f32x4 s0a = {0.f, 0.f, 0.f, 0.f}, s1a = {0.f, 0.f, 0.f, 0.f};
        f32x4 s0b = {0.f, 0.f, 0.f, 0.f}, s1b = {0.f, 0.f, 0.f, 0.f};
#pragma unroll
        for (int ks = 0; ks < 6; ks++) {
            const int kc = ks * 32 + quad * 8;
            bf16x8 bh0 = *(const bf16x8*)&sHh[tx][kc];
            bf16x8 bl0 = *(const bf16x8*)&sHl[tx][kc];
            bf16x8 bh1 = *(const bf16x8*)&sHh[16 + tx][kc];
            bf16x8 bl1 = *(const bf16x8*)&sHl[16 + tx][kc];
            s0a = __builtin_amdgcn_mfma_f32_16x16x32_bf16(Ah[ks], bh0, s0a, 0, 0, 0);
            s1a = __builtin_amdgcn_mfma_f32_16x16x32_bf16(Ah[ks], bl0, s1a, 0, 0, 0);
            s1a = __builtin_amdgcn_mfma_f32_16x16x32_bf16(Al[ks], bh0, s1a, 0, 0, 0);
            s0b = __builtin_amdgcn_mfma_f32_16x16x32_bf16(Ah[ks], bh1, s0b, 0, 0, 0);
            s1b = __builtin_amdgcn_mfma_f32_16x16x32_bf16(Ah[ks], bl1, s1b, 0, 0, 0);
            s1b = __builtin_amdgcn_mfma_f32_16x16x32_bf16(Al[ks], bh1, s1b, 0, 0, 0);
        }
        float sv0[4], sv1[4];
        const bool okA = (u0 + tx) < ue, okB = (u0 + 16 + tx) < ue;
#pragma unroll
        for (int r = 0; r < 4; r++) {
            sv0[r] = okA ? (s0a[r] + s1a[r]) : -1e30f;
            sv1[r] = okB ? (s0b[r] + s1b[r]) : -1e30f;
        }

        float alpha[4];
#pragma unroll
        for (int r = 0; r < 4; r++) {
            float mx = fmaxf(sv0[r], sv1[r]);
            mx = fmaxf(mx, __shfl_xor(mx, 1));
            mx = fmaxf(mx, __shfl_xor(mx, 2));
            mx = fmaxf(mx, __shfl_xor(mx, 4));
            mx = fmaxf(mx, __shfl_xor(mx, 8));
            float mn = fmaxf(m_s[r], mx);
            alpha[r] = __expf(m_s[r] - mn);
            float p0 = __expf(sv0[r] - mn);
            float p1 = __expf(sv1[r] - mn);
            sP[w * 16 + quad * 4 + r][tx]      = f2bf(p0);
            sP[w * 16 + quad * 4 + r][16 + tx] = f2bf(p1);
            float s = p0 + p1;
            s += __shfl_xor(s, 1);
            s += __shfl_xor(s, 2);
            s += __shfl_xor(s, 4);
            s += __shfl_xor(s, 8);
            l_s[r] = l_s[r] * alpha[r] + s;
            m_s[r] = mn;
        }
        f32x4 alv = {alpha[0], alpha[1], alpha[2], alpha[3]};
#pragma unroll
        for (int j = 0; j < 12; j++) accO[j] *= alv;
        __syncthreads();

        bf16x8 pa = *(const bf16x8*)&sP[w * 16 + tx][quad * 8];
#pragma unroll
        for (int j = 0; j < 12; j++) {
            bf16x8 hb = *(const bf16x8*)&sHt[j * 16 + tx][quad * 8];
            accO[j] = __builtin_amdgcn_mfma_f32_16x16x32_bf16(pa, hb, accO[j], 0, 0, 0);
        }
    }

#pragma unroll
    for (int r = 0; r < 4; r++) {
        int c = c0 + w * 16 + quad * 4 + r;
        if (c < CN_) {
            float* orow = Op + (((size_t)sp * B_ + b) * CN_ + c) * HD_;
#pragma unroll
            for (int j = 0; j < 12; j++) orow[j * 16 + tx] = accO[j][r];
            if (tx == 0) {
                size_t mi = ((size_t)sp * B_ + b) * CN_ + c;
                Ml[mi] = m_s[r];
                Ll[mi] = l_s[r];
            }
        }
    }
}

// ---------------------------------------------------------------------------
// K4: merge the two u-half partials.
// ---------------------------------------------------------------------------
__global__ __launch_bounds__(192) void k_merge(const float* __restrict__ Op,
                                               const float* __restrict__ Ml,
                                               const float* __restrict__ Ll,
                                               float* __restrict__ out) {
    const int c = blockIdx.x, b = blockIdx.y, h = threadIdx.x;
    const size_t i0 = (size_t)b * CN_ + c;
    const size_t i1 = (size_t)B_ * CN_ + i0;
    float m0 = Ml[i0], m1 = Ml[i1];
    float l0 = Ll[i0], l1 = Ll[i1];
    float M  = fmaxf(m0, m1);
    float e0 = __expf(m0 - M), e1 = __expf(m1 - M);
    float L  = l0 * e0 + l1 * e1;
    float o0 = Op[i0 * HD_ + h], o1 = Op[i1 * HD_ + h];
    out[i0 * HD_ + h] = (o0 * e0 + o1 * e1) / L;
}

// ---------------------------------------------------------------------------
extern "C" void kernel_launch(void* const* d_in, const int* in_sizes, int n_in,
                              void* d_out, int out_size, void* d_ws, size_t ws_size,
                              hipStream_t stream) {
    const float* X  = (const float*)d_in[0];
    const float* H  = (const float*)d_in[1];
    const float* W1 = (const float*)d_in[2];
    const float* W2 = (const float*)d_in[3];
    float* out = (float*)d_out;

    char* ws = (char*)d_ws;
    u16*   Ysh  = (u16*)(ws);                    //   8,478,720
    u16*   Ysl  = (u16*)(ws + 8478720);          //   8,478,720
    u16*   Hh   = (u16*)(ws + 16957440);         //  33,914,880
    u16*   Hl   = (u16*)(ws + 50872320);         //  33,914,880
    u16*   Hth  = (u16*)(ws + 84787200);         //  34,209,792
    u16*   Xth  = (u16*)(ws + 118996992);        //  17,301,504  (aliased by Op later)
    u16*   Xtl  = (u16*)(ws + 136298496);        //  17,301,504
    float* Op   = (float*)(ws + 118996992);      //  33,914,880  (aliases Xth+Xtl; k12 done first)
    u16*   W2h  = (u16*)(ws + 153600000);        //   1,081,344
    u16*   W2l  = (u16*)(ws + 154681344);        //   1,081,344
    u16*   W1th = (u16*)(ws + 155762688);        //      36,864
    u16*   W1tl = (u16*)(ws + 155799552);        //      36,864
    float* Ml   = (float*)(ws + 155836416);      //     176,640
    float* Ll   = (float*)(ws + 156013056);      //     176,640  -> end 156,189,696

    k0_split<<<dim3(1024),      256, 0, stream>>>(H, Hh, Hl);
    k0_tr   <<<dim3(22, 3, B_), 256, 0, stream>>>(H, Hth);
    k0_x    <<<dim3(22, B_),    256, 0, stream>>>(X, Xth, Xtl);
    k0_w2   <<<dim3(1056),      256, 0, stream>>>(W2, W2h, W2l);
    k0_w1   <<<dim3(72),        256, 0, stream>>>(W1, W1th, W1tl);
    k12_mfma<<<dim3(6, B_),     256, 0, stream>>>(W2h, W2l, Xth, Xtl, W1th, W1tl, Ysh, Ysl);
    k3_mfma <<<dim3(6, B_, 2),  256, 0, stream>>>(Ysh, Ysl, Hh, Hl, Hth, Op, Ml, Ll);
    k_merge <<<dim3(CN_, B_),   192, 0, stream>>>(Op, Ml, Ll, out);
}

// Round 5
// 501.867 us; speedup vs baseline: 2.1809x; 1.0619x over previous
//
#include <hip/hip_runtime.h>
#include <math.h>

namespace {
constexpr int B_  = 64;
constexpr int T_  = 1380;
constexpr int XD_ = 96;
constexpr int HD_ = 192;
constexpr int CN_ = 345;
constexpr int CP_ = 384;                       // padded CN for W2h rows
constexpr int TP_ = 1392;                      // padded T for Hth rows (16B mult)
constexpr int TP2_ = 1408;                     // padded T for k12 K-dim (22*64)
constexpr int TH_ = 690;                       // T/2 (u-split in k3)
constexpr float SCALE_ = 0.00736569563735987f; // 1/sqrt(96*192)
}

typedef __attribute__((ext_vector_type(8))) short bf16x8;
typedef __attribute__((ext_vector_type(4))) float f32x4;
typedef unsigned short u16;
typedef unsigned int   u32;

__device__ __forceinline__ u16 f2bf(float f) {
    union { float f; u32 u; } c; c.f = f;
    u32 r = (c.u + 0x7fffu + ((c.u >> 16) & 1u)) >> 16;
    return (u16)r;
}
__device__ __forceinline__ float bf2f(u16 s) {
    union { u32 u; float f; } c; c.u = ((u32)s) << 16;
    return c.f;
}

// ---------------------------------------------------------------------------
// K0a: split H into bf16 hi/lo, [b][u][h] layout (coalesced)
// ---------------------------------------------------------------------------
__global__ __launch_bounds__(256) void k0_split(const float* __restrict__ Hg,
                                                u16* __restrict__ Hh,
                                                u16* __restrict__ Hl) {
    const size_t n = (size_t)B_ * T_ * HD_ / 2;
    for (size_t i = (size_t)blockIdx.x * 256 + threadIdx.x; i < n;
         i += (size_t)gridDim.x * 256) {
        float2 v = ((const float2*)Hg)[i];
        u16 hx = f2bf(v.x), hy = f2bf(v.y);
        u16 lx = f2bf(v.x - bf2f(hx)), ly = f2bf(v.y - bf2f(hy));
        ((u32*)Hh)[i] = (u32)hx | ((u32)hy << 16);
        ((u32*)Hl)[i] = (u32)lx | ((u32)ly << 16);
    }
}

// ---------------------------------------------------------------------------
// K0b: Hth[b][h][u] = bf16_hi(H[b][u][h]), row stride TP_ shorts.
// ---------------------------------------------------------------------------
__global__ __launch_bounds__(256) void k0_tr(const float* __restrict__ Hg,
                                             u16* __restrict__ Hth) {
    __shared__ u16 til[64][68];
    const int tid = threadIdx.x;
    const int u0 = blockIdx.x * 64, h0 = blockIdx.y * 64, b = blockIdx.z;
#pragma unroll
    for (int i = 0; i < 16; i++) {
        int lin = i * 256 + tid;
        int r = lin >> 6, c = lin & 63;
        int u = u0 + r;
        float v = (u < T_) ? Hg[((size_t)b * T_ + u) * HD_ + h0 + c] : 0.f;
        til[c][r] = f2bf(v);
    }
    __syncthreads();
#pragma unroll
    for (int i = 0; i < 4; i++) {
        int lin = i * 256 + tid;
        int hh = lin >> 4, cc = lin & 15;
        int u = u0 + cc * 4;
        if (u + 4 <= T_) {
            ushort4 v;
            v.x = til[hh][cc * 4 + 0];
            v.y = til[hh][cc * 4 + 1];
            v.z = til[hh][cc * 4 + 2];
            v.w = til[hh][cc * 4 + 3];
            *(ushort4*)(Hth + ((size_t)b * HD_ + h0 + hh) * TP_ + u) = v;
        }
    }
}

// ---------------------------------------------------------------------------
// K0c: X -> Xth/Xtl [b][x][t] bf16 hi/lo, t padded to TP2_ with zeros.
// ---------------------------------------------------------------------------
__global__ __launch_bounds__(256) void k0_x(const float* __restrict__ Xg,
                                            u16* __restrict__ Xth,
                                            u16* __restrict__ Xtl) {
    __shared__ __align__(16) u16 tih[96][72];
    __shared__ __align__(16) u16 til[96][72];
    const int tid = threadIdx.x;
    const int t0 = blockIdx.x * 64, b = blockIdx.y;
#pragma unroll
    for (int i = 0; i < 24; i++) {
        int lin = i * 256 + tid;
        int r = lin / 96, x = lin % 96;
        float v = (t0 + r < T_) ? Xg[((size_t)b * T_ + t0 + r) * XD_ + x] : 0.f;
        u16 hi = f2bf(v);
        tih[x][r] = hi;
        til[x][r] = f2bf(v - bf2f(hi));
    }
    __syncthreads();
#pragma unroll
    for (int i = 0; i < 6; i++) {
        int id = i * 256 + tid;
        int buf = (id >= 768);
        int cid = buf ? id - 768 : id;
        int x = cid >> 3, col = cid & 7;
        uint4 v = *(const uint4*)&(buf ? til : tih)[x][col * 8];
        u16* dst = (buf ? Xtl : Xth) + ((size_t)b * XD_ + x) * TP2_ + t0 + col * 8;
        *(uint4*)dst = v;
    }
}

// ---------------------------------------------------------------------------
// K0d: W2 -> W2h/W2l [CP_][TP2_] bf16 hi/lo, zero padded both dims.
// ---------------------------------------------------------------------------
__global__ __launch_bounds__(256) void k0_w2(const float* __restrict__ W2g,
                                             u16* __restrict__ W2h,
                                             u16* __restrict__ W2l) {
    const int n = CP_ * (TP2_ / 2);
    for (int i = blockIdx.x * 256 + threadIdx.x; i < n; i += gridDim.x * 256) {
        int c = i / (TP2_ / 2), tc = i % (TP2_ / 2);
        int t = tc * 2;
        float v0 = 0.f, v1 = 0.f;
        if (c < CN_) {
            if (t < T_)     v0 = W2g[(size_t)c * T_ + t];
            if (t + 1 < T_) v1 = W2g[(size_t)c * T_ + t + 1];
        }
        u16 h0 = f2bf(v0), h1 = f2bf(v1);
        u16 l0 = f2bf(v0 - bf2f(h0)), l1 = f2bf(v1 - bf2f(h1));
        ((u32*)W2h)[i] = (u32)h0 | ((u32)h1 << 16);
        ((u32*)W2l)[i] = (u32)l0 | ((u32)l1 << 16);
    }
}

// ---------------------------------------------------------------------------
// K0e: W1 [x][h] -> W1th/W1tl [h][x] bf16 hi/lo (tiny).
// ---------------------------------------------------------------------------
__global__ __launch_bounds__(256) void k0_w1(const float* __restrict__ W1g,
                                             u16* __restrict__ W1th,
                                             u16* __restrict__ W1tl) {
    int i = blockIdx.x * 256 + threadIdx.x;
    if (i < HD_ * XD_) {
        int h = i / XD_, x = i % XD_;
        float v = W1g[(size_t)x * HD_ + h];
        u16 hi = f2bf(v);
        W1th[i] = hi;
        W1tl[i] = f2bf(v - bf2f(hi));
    }
}

// ---------------------------------------------------------------------------
// K12: fused MFMA GEMM.  Phase 1: Z[c,x] = W2@X[b] (split-bf16, K=1408).
// Phase 2: Y = SCALE * Z @ W1 (split-bf16, B-frags straight from global).
// grid (6, B), block 256 = 4 waves, c-tile 64.
// __launch_bounds__(256, 2): 128-VGPR budget so the pf[10] prefetch buffer
// (40 VGPRs) stays in registers — at default bounds the compiler capped at 72
// VGPRs and spilled pf to scratch (R4: 294 MB WRITE_SIZE, 172 us).
// ---------------------------------------------------------------------------
__global__ __launch_bounds__(256, 2) void k12_mfma(const u16* __restrict__ W2h,
                                                   const u16* __restrict__ W2l,
                                                   const u16* __restrict__ Xth,
                                                   const u16* __restrict__ Xtl,
                                                   const u16* __restrict__ W1th,
                                                   const u16* __restrict__ W1tl,
                                                   u16* __restrict__ Ysh,
                                                   u16* __restrict__ Ysl) {
    __shared__ __align__(16) char smem[46080];
    u16* sAh = (u16*)smem;                  // 64 x 72
    u16* sAl = (u16*)(smem + 9216);
    u16* sBh = (u16*)(smem + 18432);        // 96 x 72
    u16* sBl = (u16*)(smem + 32256);
    float* sZ = (float*)smem;               // phase 2: 64 x 100 fp32

    const int tid  = threadIdx.x;
    const int lane = tid & 63;
    const int w    = tid >> 6;
    const int tx   = lane & 15;
    const int quad = lane >> 4;
    const int b    = blockIdx.y;
    const int c0   = blockIdx.x * 64;

    f32x4 accZ[6];
#pragma unroll
    for (int j = 0; j < 6; j++) accZ[j] = (f32x4){0.f, 0.f, 0.f, 0.f};

    uint4 pf[10];
    // ---- prefetch step 0
    {
        const int k0 = 0;
#pragma unroll
        for (int i = 0; i < 4; i++) {
            int id = tid + i * 256;
            int buf = id >> 9, cid = id & 511;
            int row = cid >> 3, col = cid & 7;
            pf[i] = *(const uint4*)((buf ? W2l : W2h) + (size_t)(c0 + row) * TP2_ + k0 + col * 8);
        }
#pragma unroll
        for (int i = 0; i < 6; i++) {
            int id = tid + i * 256;
            int buf = (id >= 768) ? 1 : 0;
            int cid = id - buf * 768;
            int row = cid >> 3, col = cid & 7;
            pf[4 + i] = *(const uint4*)((buf ? Xtl : Xth) + ((size_t)b * XD_ + row) * TP2_ + k0 + col * 8);
        }
    }

    for (int s = 0; s < 22; s++) {
        __syncthreads();
        // ---- commit prefetched tile to LDS
#pragma unroll
        for (int i = 0; i < 4; i++) {
            int id = tid + i * 256;
            int buf = id >> 9, cid = id & 511;
            int row = cid >> 3, col = cid & 7;
            *(uint4*)((buf ? sAl : sAh) + row * 72 + col * 8) = pf[i];
        }
#pragma unroll
        for (int i = 0; i < 6; i++) {
            int id = tid + i * 256;
            int buf = (id >= 768) ? 1 : 0;
            int cid = id - buf * 768;
            int row = cid >> 3, col = cid & 7;
            *(uint4*)((buf ? sBl : sBh) + row * 72 + col * 8) = pf[4 + i];
        }
        // ---- prefetch next tile
        if (s < 21) {
            const int k0 = (s + 1) * 64;
#pragma unroll
            for (int i = 0; i < 4; i++) {
                int id = tid + i * 256;
                int buf = id >> 9, cid = id & 511;
                int row = cid >> 3, col = cid & 7;
                pf[i] = *(const uint4*)((buf ? W2l : W2h) + (size_t)(c0 + row) * TP2_ + k0 + col * 8);
            }
#pragma unroll
            for (int i = 0; i < 6; i++) {
                int id = tid + i * 256;
                int buf = (id >= 768) ? 1 : 0;
                int cid = id - buf * 768;
                int row = cid >> 3, col = cid & 7;
                pf[4 + i] = *(const uint4*)((buf ? Xtl : Xth) + ((size_t)b * XD_ + row) * TP2_ + k0 + col * 8);
            }
        }
        __syncthreads();
        // ---- compute: 2 x k32 sub-steps, 6 n-tiles, 3 split terms
#pragma unroll
        for (int sub = 0; sub < 2; sub++) {
            const int kc = sub * 32 + quad * 8;
            bf16x8 ah = *(const bf16x8*)(sAh + (w * 16 + tx) * 72 + kc);
            bf16x8 al = *(const bf16x8*)(sAl + (w * 16 + tx) * 72 + kc);
#pragma unroll
            for (int nt = 0; nt < 6; nt++) {
                bf16x8 bh = *(const bf16x8*)(sBh + (nt * 16 + tx) * 72 + kc);
                bf16x8 bl = *(const bf16x8*)(sBl + (nt * 16 + tx) * 72 + kc);
                accZ[nt] = __builtin_amdgcn_mfma_f32_16x16x32_bf16(ah, bh, accZ[nt], 0, 0, 0);
                accZ[nt] = __builtin_amdgcn_mfma_f32_16x16x32_bf16(ah, bl, accZ[nt], 0, 0, 0);
                accZ[nt] = __builtin_amdgcn_mfma_f32_16x16x32_bf16(al, bh, accZ[nt], 0, 0, 0);
            }
        }
    }

    // ---- phase 2: Y = SCALE * Z @ W1
    __syncthreads();
#pragma unroll
    for (int nt = 0; nt < 6; nt++)
#pragma unroll
        for (int r = 0; r < 4; r++)
            sZ[(w * 16 + quad * 4 + r) * 100 + nt * 16 + tx] = accZ[nt][r];
    __syncthreads();

    bf16x8 A2h[3], A2l[3];
#pragma unroll
    for (int ks = 0; ks < 3; ks++) {
        const float* zrow = sZ + (w * 16 + tx) * 100 + ks * 32 + quad * 8;
        bf16x8 vh, vl;
#pragma unroll
        for (int j = 0; j < 8; j++) {
            float v = zrow[j];
            u16 hi = f2bf(v);
            vh[j] = (short)hi;
            vl[j] = (short)f2bf(v - bf2f(hi));
        }
        A2h[ks] = vh; A2l[ks] = vl;
    }

    f32x4 accY[12];
#pragma unroll
    for (int j = 0; j < 12; j++) accY[j] = (f32x4){0.f, 0.f, 0.f, 0.f};
#pragma unroll
    for (int nt = 0; nt < 12; nt++) {
        const int hrow = nt * 16 + tx;
#pragma unroll
        for (int ks = 0; ks < 3; ks++) {
            bf16x8 bh = *(const bf16x8*)(W1th + (size_t)hrow * XD_ + ks * 32 + quad * 8);
            bf16x8 bl = *(const bf16x8*)(W1tl + (size_t)hrow * XD_ + ks * 32 + quad * 8);
            accY[nt] = __builtin_amdgcn_mfma_f32_16x16x32_bf16(A2h[ks], bh, accY[nt], 0, 0, 0);
            accY[nt] = __builtin_amdgcn_mfma_f32_16x16x32_bf16(A2h[ks], bl, accY[nt], 0, 0, 0);
            accY[nt] = __builtin_amdgcn_mfma_f32_16x16x32_bf16(A2l[ks], bh, accY[nt], 0, 0, 0);
        }
    }

#pragma unroll
    for (int r = 0; r < 4; r++) {
        int c = c0 + w * 16 + quad * 4 + r;
        if (c < CN_) {
            size_t base = ((size_t)b * CN_ + c) * HD_;
#pragma unroll
            for (int nt = 0; nt < 12; nt++) {
                float y = SCALE_ * accY[nt][r];
                u16 hi = f2bf(y);
                Ysh[base + nt * 16 + tx] = hi;
                Ysl[base + nt * 16 + tx] = f2bf(y - bf2f(hi));
            }
        }
    }
}

// ---------------------------------------------------------------------------
// K3: MFMA flash attention over a u-half.  grid (6, B, 2), block 256 = 4 waves.
// ---------------------------------------------------------------------------
__global__ __launch_bounds__(256, 3) void k3_mfma(const u16* __restrict__ Ysh,
                                                  const u16* __restrict__ Ysl,
                                                  const u16* __restrict__ Hh,
                                                  const u16* __restrict__ Hl,
                                                  const u16* __restrict__ Hth,
                                                  float* __restrict__ Op,
                                                  float* __restrict__ Ml,
                                                  float* __restrict__ Ll) {
    __shared__ __align__(16) u16 sHh[32][200];
    __shared__ __align__(16) u16 sHl[32][200];
    __shared__ __align__(16) u16 sHt[192][40];
    __shared__ __align__(16) u16 sP[64][40];

    const int tid  = threadIdx.x;
    const int lane = tid & 63;
    const int w    = tid >> 6;
    const int tx   = lane & 15;
    const int quad = lane >> 4;
    const int b    = blockIdx.y;
    const int c0   = blockIdx.x * 64;
    const int sp   = blockIdx.z;
    const int us   = sp * TH_, ue = us + TH_;

    bf16x8 Ah[6], Al[6];
    const int ar = c0 + w * 16 + tx;
    if (ar < CN_) {
        const u16* yh = Ysh + ((size_t)b * CN_ + ar) * HD_;
        const u16* yl = Ysl + ((size_t)b * CN_ + ar) * HD_;
#pragma unroll
        for (int ks = 0; ks < 6; ks++) {
            Ah[ks] = *(const bf16x8*)(yh + ks * 32 + quad * 8);
            Al[ks] = *(const bf16x8*)(yl + ks * 32 + quad * 8);
        }
    } else {
#pragma unroll
        for (int ks = 0; ks < 6; ks++) { Ah[ks] = (bf16x8)0; Al[ks] = (bf16x8)0; }
    }

    float m_s[4], l_s[4];
    f32x4 accO[12];
#pragma unroll
    for (int r = 0; r < 4; r++) { m_s[r] = -1e30f; l_s[r] = 0.f; }
#pragma unroll
    for (int j = 0; j < 12; j++) accO[j] = (f32x4){0.f, 0.f, 0.f, 0.f};

    const u16* srch = Hh + (size_t)b * T_ * HD_;
    const u16* srcl = Hl + (size_t)b * T_ * HD_;
    const u16* srct = Hth + (size_t)b * HD_ * TP_;

    for (int t = 0; t < 22; t++) {
        const int u0 = us + t * 32;
        __syncthreads();
#pragma unroll
        for (int i = 0; i < 3; i++) {
            int cid = tid + i * 256;
            int u = cid / 24, c = cid % 24;
            uint4 vh = {0, 0, 0, 0}, vl = {0, 0, 0, 0};
            if (u0 + u < ue) {
                vh = *(const uint4*)(srch + ((size_t)(u0 + u)) * HD_ + c * 8);
                vl = *(const uint4*)(srcl + ((size_t)(u0 + u)) * HD_ + c * 8);
            }
            *(uint4*)&sHh[u][c * 8] = vh;
            *(uint4*)&sHl[u][c * 8] = vl;
        }
#pragma unroll
        for (int i = 0; i < 3; i++) {
            int cid = tid + i * 256;
            int h = cid >> 2, cc = cid & 3;
            int ub = u0 + cc * 8;
            uint4 v = {0, 0, 0, 0};
            if (ub + 8 <= ue) {
                v = *(const uint4*)(srct + (size_t)h * TP_ + ub);
            } else if (ub < ue) {
                const u16* p = srct + (size_t)h * TP_;
                u32 w0 = 0, w1 = 0, w2 = 0, w3 = 0;
                if (ub + 0 < ue) w0 |= (u32)p[ub + 0];
                if (ub + 1 < ue) w0 |= (u32)p[ub + 1] << 16;
                if (ub + 2 < ue) w1 |= (u32)p[ub + 2];
                if (ub + 3 < ue) w1 |= (u32)p[ub + 3] << 16;
                if (ub + 4 < ue) w2 |= (u32)p[ub + 4];
                if (ub + 5 < ue) w2 |= (u32)p[ub + 5] << 16;
                if (ub + 6 < ue) w3 |= (u32)p[ub + 6];
                if (ub + 7 < ue) w3 |= (u32)p[ub + 7] << 16;
                v = make_uint4(w0, w1, w2, w3);
            }
            *(uint4*)&sHt[h][cc * 8] = v;
        }
        __syncthreads();

        f32x4 s0a = {0.f, 0.f, 0.f, 0.f}, s1a = {0.f, 0.f, 0.f, 0.f};
        f32x4 s0b = {0.f, 0.f, 0.f, 0.f}, s1b = {0.f, 0.f, 0.f, 0.f};
#pragma unroll
        for (int ks = 0; ks < 6; ks++) {
            const int kc = ks * 32 + quad * 8;
            bf16x8 bh0 = *(const bf16x8*)&sHh[tx][kc];
            bf16x8 bl0 = *(const bf16x8*)&sHl[tx][kc];
            bf16x8 bh1 = *(const bf16x8*)&sHh[16 + tx][kc];
            bf16x8 bl1 = *(const bf16x8*)&sHl[16 + tx][kc];
            s0a = __builtin_amdgcn_mfma_f32_16x16x32_bf16(Ah[ks], bh0, s0a, 0, 0, 0);
            s1a = __builtin_amdgcn_mfma_f32_16x16x32_bf16(Ah[ks], bl0, s1a, 0, 0, 0);
            s1a = __builtin_amdgcn_mfma_f32_16x16x32_bf16(Al[ks], bh0, s1a, 0, 0, 0);
            s0b = __builtin_amdgcn_mfma_f32_16x16x32_bf16(Ah[ks], bh1, s0b, 0, 0, 0);
            s1b = __builtin_amdgcn_mfma_f32_16x16x32_bf16(Ah[ks], bl1, s1b, 0, 0, 0);
            s1b = __builtin_amdgcn_mfma_f32_16x16x32_bf16(Al[ks], bh1, s1b, 0, 0, 0);
        }
        float sv0[4], sv1[4];
        const bool okA = (u0 + tx) < ue, okB = (u0 + 16 + tx) < ue;
#pragma unroll
        for (int r = 0; r < 4; r++) {
            sv0[r] = okA ? (s0a[r] + s1a[r]) : -1e30f;
            sv1[r] = okB ? (s0b[r] + s1b[r]) : -1e30f;
        }

        float alpha[4];
#pragma unroll
        for (int r = 0; r < 4; r++) {
            float mx = fmaxf(sv0[r], sv1[r]);
            mx = fmaxf(mx, __shfl_xor(mx, 1));
            mx = fmaxf(mx, __shfl_xor(mx, 2));
            mx = fmaxf(mx, __shfl_xor(mx, 4));
            mx = fmaxf(mx, __shfl_xor(mx, 8));
            float mn = fmaxf(m_s[r], mx);
            alpha[r] = __expf(m_s[r] - mn);
            float p0 = __expf(sv0[r] - mn);
            float p1 = __expf(sv1[r] - mn);
            sP[w * 16 + quad * 4 + r][tx]      = f2bf(p0);
            sP[w * 16 + quad * 4 + r][16 + tx] = f2bf(p1);
            float s = p0 + p1;
            s += __shfl_xor(s, 1);
            s += __shfl_xor(s, 2);
            s += __shfl_xor(s, 4);
            s += __shfl_xor(s, 8);
            l_s[r] = l_s[r] * alpha[r] + s;
            m_s[r] = mn;
        }
        f32x4 alv = {alpha[0], alpha[1], alpha[2], alpha[3]};
#pragma unroll
        for (int j = 0; j < 12; j++) accO[j] *= alv;
        __syncthreads();

        bf16x8 pa = *(const bf16x8*)&sP[w * 16 + tx][quad * 8];
#pragma unroll
        for (int j = 0; j < 12; j++) {
            bf16x8 hb = *(const bf16x8*)&sHt[j * 16 + tx][quad * 8];
            accO[j] = __builtin_amdgcn_mfma_f32_16x16x32_bf16(pa, hb, accO[j], 0, 0, 0);
        }
    }

#pragma unroll
    for (int r = 0; r < 4; r++) {
        int c = c0 + w * 16 + quad * 4 + r;
        if (c < CN_) {
            float* orow = Op + (((size_t)sp * B_ + b) * CN_ + c) * HD_;
#pragma unroll
            for (int j = 0; j < 12; j++) orow[j * 16 + tx] = accO[j][r];
            if (tx == 0) {
                size_t mi = ((size_t)sp * B_ + b) * CN_ + c;
                Ml[mi] = m_s[r];
                Ll[mi] = l_s[r];
            }
        }
    }
}

// ---------------------------------------------------------------------------
// K4: merge the two u-half partials.
// ---------------------------------------------------------------------------
__global__ __launch_bounds__(192) void k_merge(const float* __restrict__ Op,
                                               const float* __restrict__ Ml,
                                               const float* __restrict__ Ll,
                                               float* __restrict__ out) {
    const int c = blockIdx.x, b = blockIdx.y, h = threadIdx.x;
    const size_t i0 = (size_t)b * CN_ + c;
    const size_t i1 = (size_t)B_ * CN_ + i0;
    float m0 = Ml[i0], m1 = Ml[i1];
    float l0 = Ll[i0], l1 = Ll[i1];
    float M  = fmaxf(m0, m1);
    float e0 = __expf(m0 - M), e1 = __expf(m1 - M);
    float L  = l0 * e0 + l1 * e1;
    float o0 = Op[i0 * HD_ + h], o1 = Op[i1 * HD_ + h];
    out[i0 * HD_ + h] = (o0 * e0 + o1 * e1) / L;
}

// ---------------------------------------------------------------------------
extern "C" void kernel_launch(void* const* d_in, const int* in_sizes, int n_in,
                              void* d_out, int out_size, void* d_ws, size_t ws_size,
                              hipStream_t stream) {
    const float* X  = (const float*)d_in[0];
    const float* H  = (const float*)d_in[1];
    const float* W1 = (const float*)d_in[2];
    const float* W2 = (const float*)d_in[3];
    float* out = (float*)d_out;

    char* ws = (char*)d_ws;
    u16*   Ysh  = (u16*)(ws);                    //   8,478,720
    u16*   Ysl  = (u16*)(ws + 8478720);          //   8,478,720
    u16*   Hh   = (u16*)(ws + 16957440);         //  33,914,880
    u16*   Hl   = (u16*)(ws + 50872320);         //  33,914,880
    u16*   Hth  = (u16*)(ws + 84787200);         //  34,209,792
    u16*   Xth  = (u16*)(ws + 118996992);        //  17,301,504  (aliased by Op later)
    u16*   Xtl  = (u16*)(ws + 136298496);        //  17,301,504
    float* Op   = (float*)(ws + 118996992);      //  33,914,880  (aliases Xth+Xtl; k12 done first)
    u16*   W2h  = (u16*)(ws + 153600000);        //   1,081,344
    u16*   W2l  = (u16*)(ws + 154681344);        //   1,081,344
    u16*   W1th = (u16*)(ws + 155762688);        //      36,864
    u16*   W1tl = (u16*)(ws + 155799552);        //      36,864
    float* Ml   = (float*)(ws + 155836416);      //     176,640
    float* Ll   = (float*)(ws + 156013056);      //     176,640  -> end 156,189,696

    k0_split<<<dim3(1024),      256, 0, stream>>>(H, Hh, Hl);
    k0_tr   <<<dim3(22, 3, B_), 256, 0, stream>>>(H, Hth);
    k0_x    <<<dim3(22, B_),    256, 0, stream>>>(X, Xth, Xtl);
    k0_w2   <<<dim3(1056),      256, 0, stream>>>(W2, W2h, W2l);
    k0_w1   <<<dim3(72),        256, 0, stream>>>(W1, W1th, W1tl);
    k12_mfma<<<dim3(6, B_),     256, 0, stream>>>(W2h, W2l, Xth, Xtl, W1th, W1tl, Ysh, Ysl);
    k3_mfma <<<dim3(6, B_, 2),  256, 0, stream>>>(Ysh, Ysl, Hh, Hl, Hth, Op, Ml, Ll);
    k_merge <<<dim3(CN_, B_),   192, 0, stream>>>(Op, Ml, Ll, out);
}

// Round 6
// 484.088 us; speedup vs baseline: 2.2610x; 1.0367x over previous
//
#include <hip/hip_runtime.h>
#include <math.h>

namespace {
constexpr int B_  = 64;
constexpr int T_  = 1380;
constexpr int XD_ = 96;
constexpr int HD_ = 192;
constexpr int CN_ = 345;
constexpr int CP_ = 384;                       // padded CN
constexpr int TP_ = 1392;                      // padded T for Hth rows
constexpr int TP2_ = 1408;                     // padded T for k12 K-dim (22*64)
constexpr int TH_ = 690;                       // T/2 (u-split in k3)
constexpr float SCALE_ = 0.00736569563735987f; // 1/sqrt(96*192)
}

typedef __attribute__((ext_vector_type(8))) short bf16x8;
typedef __attribute__((ext_vector_type(4))) float f32x4;
typedef unsigned short u16;
typedef unsigned int   u32;

__device__ __forceinline__ u16 f2bf(float f) {
    union { float f; u32 u; } c; c.f = f;
    u32 r = (c.u + 0x7fffu + ((c.u >> 16) & 1u)) >> 16;
    return (u16)r;
}
__device__ __forceinline__ float bf2f(u16 s) {
    union { u32 u; float f; } c; c.u = ((u32)s) << 16;
    return c.f;
}

// ---------------------------------------------------------------------------
// K0h: fused H prep — one read of H produces Hh/Hl ([b][u][h] bf16 hi/lo)
// and Hth ([b][h][u] bf16 hi, row stride TP_).  grid (22, 3, B).
// ---------------------------------------------------------------------------
__global__ __launch_bounds__(256) void k0_h(const float* __restrict__ Hg,
                                            u16* __restrict__ Hh,
                                            u16* __restrict__ Hl,
                                            u16* __restrict__ Hth) {
    __shared__ u16 til[64][68];
    const int tid = threadIdx.x;
    const int u0 = blockIdx.x * 64, h0 = blockIdx.y * 64, b = blockIdx.z;
#pragma unroll
    for (int i = 0; i < 8; i++) {
        int lin = i * 256 + tid;           // 0..2047
        int r = lin >> 5;                  // u row 0..63
        int cp = lin & 31;                 // float2 col
        int u = u0 + r, h = h0 + cp * 2;
        float2 v = make_float2(0.f, 0.f);
        if (u < T_) v = *(const float2*)(Hg + ((size_t)b * T_ + u) * HD_ + h);
        u16 hx = f2bf(v.x), hy = f2bf(v.y);
        u16 lx = f2bf(v.x - bf2f(hx)), ly = f2bf(v.y - bf2f(hy));
        if (u < T_) {
            *(u32*)(Hh + ((size_t)b * T_ + u) * HD_ + h) = (u32)hx | ((u32)hy << 16);
            *(u32*)(Hl + ((size_t)b * T_ + u) * HD_ + h) = (u32)lx | ((u32)ly << 16);
        }
        til[cp * 2][r]     = hx;
        til[cp * 2 + 1][r] = hy;
    }
    __syncthreads();
#pragma unroll
    for (int i = 0; i < 4; i++) {
        int lin = i * 256 + tid;
        int hh = lin >> 4, cc = lin & 15;
        int u = u0 + cc * 4;
        if (u + 4 <= T_) {
            ushort4 v;
            v.x = til[hh][cc * 4 + 0];
            v.y = til[hh][cc * 4 + 1];
            v.z = til[hh][cc * 4 + 2];
            v.w = til[hh][cc * 4 + 3];
            *(ushort4*)(Hth + ((size_t)b * HD_ + h0 + hh) * TP_ + u) = v;
        }
    }
}

// ---------------------------------------------------------------------------
// K0c: X -> Xth/Xtl [b][x][t] bf16 hi/lo, t padded to TP2_ with zeros.
// ---------------------------------------------------------------------------
__global__ __launch_bounds__(256) void k0_x(const float* __restrict__ Xg,
                                            u16* __restrict__ Xth,
                                            u16* __restrict__ Xtl) {
    __shared__ __align__(16) u16 tih[96][72];
    __shared__ __align__(16) u16 til[96][72];
    const int tid = threadIdx.x;
    const int t0 = blockIdx.x * 64, b = blockIdx.y;
#pragma unroll
    for (int i = 0; i < 24; i++) {
        int lin = i * 256 + tid;
        int r = lin / 96, x = lin % 96;
        float v = (t0 + r < T_) ? Xg[((size_t)b * T_ + t0 + r) * XD_ + x] : 0.f;
        u16 hi = f2bf(v);
        tih[x][r] = hi;
        til[x][r] = f2bf(v - bf2f(hi));
    }
    __syncthreads();
#pragma unroll
    for (int i = 0; i < 6; i++) {
        int id = i * 256 + tid;
        int buf = (id >= 768);
        int cid = buf ? id - 768 : id;
        int x = cid >> 3, col = cid & 7;
        uint4 v = *(const uint4*)&(buf ? til : tih)[x][col * 8];
        u16* dst = (buf ? Xtl : Xth) + ((size_t)b * XD_ + x) * TP2_ + t0 + col * 8;
        *(uint4*)dst = v;
    }
}

// ---------------------------------------------------------------------------
// K0d: W2 -> W2h/W2l [CP_][TP2_] bf16 hi/lo, zero padded both dims.
// ---------------------------------------------------------------------------
__global__ __launch_bounds__(256) void k0_w2(const float* __restrict__ W2g,
                                             u16* __restrict__ W2h,
                                             u16* __restrict__ W2l) {
    const int n = CP_ * (TP2_ / 2);
    for (int i = blockIdx.x * 256 + threadIdx.x; i < n; i += gridDim.x * 256) {
        int c = i / (TP2_ / 2), tc = i % (TP2_ / 2);
        int t = tc * 2;
        float v0 = 0.f, v1 = 0.f;
        if (c < CN_) {
            if (t < T_)     v0 = W2g[(size_t)c * T_ + t];
            if (t + 1 < T_) v1 = W2g[(size_t)c * T_ + t + 1];
        }
        u16 h0 = f2bf(v0), h1 = f2bf(v1);
        u16 l0 = f2bf(v0 - bf2f(h0)), l1 = f2bf(v1 - bf2f(h1));
        ((u32*)W2h)[i] = (u32)h0 | ((u32)h1 << 16);
        ((u32*)W2l)[i] = (u32)l0 | ((u32)l1 << 16);
    }
}

// ---------------------------------------------------------------------------
// K0e: W1 [x][h] -> W1th/W1tl [h][x] bf16 hi/lo (tiny).
// ---------------------------------------------------------------------------
__global__ __launch_bounds__(256) void k0_w1(const float* __restrict__ W1g,
                                             u16* __restrict__ W1th,
                                             u16* __restrict__ W1tl) {
    int i = blockIdx.x * 256 + threadIdx.x;
    if (i < HD_ * XD_) {
        int h = i / XD_, x = i % XD_;
        float v = W1g[(size_t)x * HD_ + h];
        u16 hi = f2bf(v);
        W1th[i] = hi;
        W1tl[i] = f2bf(v - bf2f(hi));
    }
}

// ---------------------------------------------------------------------------
// K12: fused MFMA GEMM.  Phase 1: Z[c,x] = W2@X[b] (split-bf16, K=1408).
// Phase 2: Y = SCALE * Z @ W1.  1-D grid 384, block 256 = 4 waves, c-tile 64.
// XCD swizzle: the 6 c-blocks sharing a b land on one XCD (ids == mod 8)
// so X[b] (1.05 MB) is served out of that XCD's L2 after the first touch.
// ---------------------------------------------------------------------------
__global__ __launch_bounds__(256, 2) void k12_mfma(const u16* __restrict__ W2h,
                                                   const u16* __restrict__ W2l,
                                                   const u16* __restrict__ Xth,
                                                   const u16* __restrict__ Xtl,
                                                   const u16* __restrict__ W1th,
                                                   const u16* __restrict__ W1tl,
                                                   u16* __restrict__ Ysh,
                                                   u16* __restrict__ Ysl) {
    __shared__ __align__(16) char smem[46080];
    u16* sAh = (u16*)smem;                  // 64 x 72
    u16* sAl = (u16*)(smem + 9216);
    u16* sBh = (u16*)(smem + 18432);        // 96 x 72
    u16* sBl = (u16*)(smem + 32256);
    float* sZ = (float*)smem;               // phase 2: 64 x 100 fp32

    const int tid  = threadIdx.x;
    const int lane = tid & 63;
    const int w    = tid >> 6;
    const int tx   = lane & 15;
    const int quad = lane >> 4;
    // XCD-aware decode: L = xcd + 8*slot; slot -> (b_local, cb)
    const int L    = blockIdx.x;
    const int xcd  = L & 7;
    const int slot = L >> 3;              // 0..47
    const int b    = xcd * 8 + slot / 6;
    const int c0   = (slot % 6) * 64;

    f32x4 accZ[6];
#pragma unroll
    for (int j = 0; j < 6; j++) accZ[j] = (f32x4){0.f, 0.f, 0.f, 0.f};

    uint4 pf[10];
    {
        const int k0 = 0;
#pragma unroll
        for (int i = 0; i < 4; i++) {
            int id = tid + i * 256;
            int buf = id >> 9, cid = id & 511;
            int row = cid >> 3, col = cid & 7;
            pf[i] = *(const uint4*)((buf ? W2l : W2h) + (size_t)(c0 + row) * TP2_ + k0 + col * 8);
        }
#pragma unroll
        for (int i = 0; i < 6; i++) {
            int id = tid + i * 256;
            int buf = (id >= 768) ? 1 : 0;
            int cid = id - buf * 768;
            int row = cid >> 3, col = cid & 7;
            pf[4 + i] = *(const uint4*)((buf ? Xtl : Xth) + ((size_t)b * XD_ + row) * TP2_ + k0 + col * 8);
        }
    }

    for (int s = 0; s < 22; s++) {
        __syncthreads();
#pragma unroll
        for (int i = 0; i < 4; i++) {
            int id = tid + i * 256;
            int buf = id >> 9, cid = id & 511;
            int row = cid >> 3, col = cid & 7;
            *(uint4*)((buf ? sAl : sAh) + row * 72 + col * 8) = pf[i];
        }
#pragma unroll
        for (int i = 0; i < 6; i++) {
            int id = tid + i * 256;
            int buf = (id >= 768) ? 1 : 0;
            int cid = id - buf * 768;
            int row = cid >> 3, col = cid & 7;
            *(uint4*)((buf ? sBl : sBh) + row * 72 + col * 8) = pf[4 + i];
        }
        if (s < 21) {
            const int k0 = (s + 1) * 64;
#pragma unroll
            for (int i = 0; i < 4; i++) {
                int id = tid + i * 256;
                int buf = id >> 9, cid = id & 511;
                int row = cid >> 3, col = cid & 7;
                pf[i] = *(const uint4*)((buf ? W2l : W2h) + (size_t)(c0 + row) * TP2_ + k0 + col * 8);
            }
#pragma unroll
            for (int i = 0; i < 6; i++) {
                int id = tid + i * 256;
                int buf = (id >= 768) ? 1 : 0;
                int cid = id - buf * 768;
                int row = cid >> 3, col = cid & 7;
                pf[4 + i] = *(const uint4*)((buf ? Xtl : Xth) + ((size_t)b * XD_ + row) * TP2_ + k0 + col * 8);
            }
        }
        __syncthreads();
#pragma unroll
        for (int sub = 0; sub < 2; sub++) {
            const int kc = sub * 32 + quad * 8;
            bf16x8 ah = *(const bf16x8*)(sAh + (w * 16 + tx) * 72 + kc);
            bf16x8 al = *(const bf16x8*)(sAl + (w * 16 + tx) * 72 + kc);
#pragma unroll
            for (int nt = 0; nt < 6; nt++) {
                bf16x8 bh = *(const bf16x8*)(sBh + (nt * 16 + tx) * 72 + kc);
                bf16x8 bl = *(const bf16x8*)(sBl + (nt * 16 + tx) * 72 + kc);
                accZ[nt] = __builtin_amdgcn_mfma_f32_16x16x32_bf16(ah, bh, accZ[nt], 0, 0, 0);
                accZ[nt] = __builtin_amdgcn_mfma_f32_16x16x32_bf16(ah, bl, accZ[nt], 0, 0, 0);
                accZ[nt] = __builtin_amdgcn_mfma_f32_16x16x32_bf16(al, bh, accZ[nt], 0, 0, 0);
            }
        }
    }

    __syncthreads();
#pragma unroll
    for (int nt = 0; nt < 6; nt++)
#pragma unroll
        for (int r = 0; r < 4; r++)
            sZ[(w * 16 + quad * 4 + r) * 100 + nt * 16 + tx] = accZ[nt][r];
    __syncthreads();

    bf16x8 A2h[3], A2l[3];
#pragma unroll
    for (int ks = 0; ks < 3; ks++) {
        const float* zrow = sZ + (w * 16 + tx) * 100 + ks * 32 + quad * 8;
        bf16x8 vh, vl;
#pragma unroll
        for (int j = 0; j < 8; j++) {
            float v = zrow[j];
            u16 hi = f2bf(v);
            vh[j] = (short)hi;
            vl[j] = (short)f2bf(v - bf2f(hi));
        }
        A2h[ks] = vh; A2l[ks] = vl;
    }

    f32x4 accY[12];
#pragma unroll
    for (int j = 0; j < 12; j++) accY[j] = (f32x4){0.f, 0.f, 0.f, 0.f};
#pragma unroll
    for (int nt = 0; nt < 12; nt++) {
        const int hrow = nt * 16 + tx;
#pragma unroll
        for (int ks = 0; ks < 3; ks++) {
            bf16x8 bh = *(const bf16x8*)(W1th + (size_t)hrow * XD_ + ks * 32 + quad * 8);
            bf16x8 bl = *(const bf16x8*)(W1tl + (size_t)hrow * XD_ + ks * 32 + quad * 8);
            accY[nt] = __builtin_amdgcn_mfma_f32_16x16x32_bf16(A2h[ks], bh, accY[nt], 0, 0, 0);
            accY[nt] = __builtin_amdgcn_mfma_f32_16x16x32_bf16(A2h[ks], bl, accY[nt], 0, 0, 0);
            accY[nt] = __builtin_amdgcn_mfma_f32_16x16x32_bf16(A2l[ks], bh, accY[nt], 0, 0, 0);
        }
    }

#pragma unroll
    for (int r = 0; r < 4; r++) {
        int c = c0 + w * 16 + quad * 4 + r;
        if (c < CN_) {
            size_t base = ((size_t)b * CN_ + c) * HD_;
#pragma unroll
            for (int nt = 0; nt < 12; nt++) {
                float y = SCALE_ * accY[nt][r];
                u16 hi = f2bf(y);
                Ysh[base + nt * 16 + tx] = hi;
                Ysl[base + nt * 16 + tx] = f2bf(y - bf2f(hi));
            }
        }
    }
}

// ---------------------------------------------------------------------------
// K3: MFMA flash attention over a u-half.  1-D grid 512, block 384 = 6 waves.
// c-tile 96 (1 m-tile/wave), u-tile 32, u-split 2.  XCD swizzle: the 4
// c-blocks sharing (b,sp) — which read identical H data — get ids == mod 8
// so they share one XCD's L2.  512 blocks = 2/CU exactly (balanced).
// ---------------------------------------------------------------------------
__global__ __launch_bounds__(384, 2) void k3_mfma(const u16* __restrict__ Ysh,
                                                  const u16* __restrict__ Ysl,
                                                  const u16* __restrict__ Hh,
                                                  const u16* __restrict__ Hl,
                                                  const u16* __restrict__ Hth,
                                                  float* __restrict__ Op,
                                                  float* __restrict__ Ml,
                                                  float* __restrict__ Ll) {
    __shared__ __align__(16) u16 sHh[32][200];
    __shared__ __align__(16) u16 sHl[32][200];
    __shared__ __align__(16) u16 sHt[192][40];
    __shared__ __align__(16) u16 sP[96][40];

    const int tid  = threadIdx.x;
    const int lane = tid & 63;
    const int w    = tid >> 6;            // 0..5
    const int tx   = lane & 15;
    const int quad = lane >> 4;
    // XCD-aware decode: L = xcd + 8*slot; slot -> (pair_local, cb)
    const int L    = blockIdx.x;
    const int xcd  = L & 7;
    const int slot = L >> 3;              // 0..63
    const int gp   = xcd * 16 + (slot >> 2);   // (b,sp) pair, 0..127
    const int cb   = slot & 3;
    const int b    = gp >> 1;
    const int sp   = gp & 1;
    const int c0   = cb * 96;
    const int us   = sp * TH_, ue = us + TH_;

    bf16x8 Ah[6], Al[6];
    const int ar = c0 + w * 16 + tx;
    if (ar < CN_) {
        const u16* yh = Ysh + ((size_t)b * CN_ + ar) * HD_;
        const u16* yl = Ysl + ((size_t)b * CN_ + ar) * HD_;
#pragma unroll
        for (int ks = 0; ks < 6; ks++) {
            Ah[ks] = *(const bf16x8*)(yh + ks * 32 + quad * 8);
            Al[ks] = *(const bf16x8*)(yl + ks * 32 + quad * 8);
        }
    } else {
#pragma unroll
        for (int ks = 0; ks < 6; ks++) { Ah[ks] = (bf16x8)0; Al[ks] = (bf16x8)0; }
    }

    float m_s[4], l_s[4];
    f32x4 accO[12];
#pragma unroll
    for (int r = 0; r < 4; r++) { m_s[r] = -1e30f; l_s[r] = 0.f; }
#pragma unroll
    for (int j = 0; j < 12; j++) accO[j] = (f32x4){0.f, 0.f, 0.f, 0.f};

    const u16* srch = Hh + (size_t)b * T_ * HD_;
    const u16* srcl = Hl + (size_t)b * T_ * HD_;
    const u16* srct = Hth + (size_t)b * HD_ * TP_;

    for (int t = 0; t < 22; t++) {
        const int u0 = us + t * 32;
        __syncthreads();
        // ---- stage sHh/sHl: 768 16B-chunks each, 2 iters of 384 threads
#pragma unroll
        for (int i = 0; i < 2; i++) {
            int cid = tid + i * 384;
            int u = cid / 24, c = cid % 24;
            uint4 vh = {0, 0, 0, 0}, vl = {0, 0, 0, 0};
            if (u0 + u < ue) {
                vh = *(const uint4*)(srch + ((size_t)(u0 + u)) * HD_ + c * 8);
                vl = *(const uint4*)(srcl + ((size_t)(u0 + u)) * HD_ + c * 8);
            }
            *(uint4*)&sHh[u][c * 8] = vh;
            *(uint4*)&sHl[u][c * 8] = vl;
        }
        // ---- stage sHt: 768 16B-chunks
#pragma unroll
        for (int i = 0; i < 2; i++) {
            int cid = tid + i * 384;
            int h = cid >> 2, cc = cid & 3;
            int ub = u0 + cc * 8;
            uint4 v = {0, 0, 0, 0};
            if (ub + 8 <= ue) {
                v = *(const uint4*)(srct + (size_t)h * TP_ + ub);
            } else if (ub < ue) {
                const u16* p = srct + (size_t)h * TP_;
                u32 w0 = 0, w1 = 0, w2 = 0, w3 = 0;
                if (ub + 0 < ue) w0 |= (u32)p[ub + 0];
                if (ub + 1 < ue) w0 |= (u32)p[ub + 1] << 16;
                if (ub + 2 < ue) w1 |= (u32)p[ub + 2];
                if (ub + 3 < ue) w1 |= (u32)p[ub + 3] << 16;
                if (ub + 4 < ue) w2 |= (u32)p[ub + 4];
                if (ub + 5 < ue) w2 |= (u32)p[ub + 5] << 16;
                if (ub + 6 < ue) w3 |= (u32)p[ub + 6];
                if (ub + 7 < ue) w3 |= (u32)p[ub + 7] << 16;
                v = make_uint4(w0, w1, w2, w3);
            }
            *(uint4*)&sHt[h][cc * 8] = v;
        }
        __syncthreads();

        // ---- GEMM1: S[c][u], K=192, split-bf16 (hi*hi + hi*lo + lo*hi)
        f32x4 s0a = {0.f, 0.f, 0.f, 0.f}, s1a = {0.f, 0.f, 0.f, 0.f};
        f32x4 s0b = {0.f, 0.f, 0.f, 0.f}, s1b = {0.f, 0.f, 0.f, 0.f};
#pragma unroll
        for (int ks = 0; ks < 6; ks++) {
            const int kc = ks * 32 + quad * 8;
            bf16x8 bh0 = *(const bf16x8*)&sHh[tx][kc];
            bf16x8 bl0 = *(const bf16x8*)&sHl[tx][kc];
            bf16x8 bh1 = *(const bf16x8*)&sHh[16 + tx][kc];
            bf16x8 bl1 = *(const bf16x8*)&sHl[16 + tx][kc];
            s0a = __builtin_amdgcn_mfma_f32_16x16x32_bf16(Ah[ks], bh0, s0a, 0, 0, 0);
            s1a = __builtin_amdgcn_mfma_f32_16x16x32_bf16(Ah[ks], bl0, s1a, 0, 0, 0);
            s1a = __builtin_amdgcn_mfma_f32_16x16x32_bf16(Al[ks], bh0, s1a, 0, 0, 0);
            s0b = __builtin_amdgcn_mfma_f32_16x16x32_bf16(Ah[ks], bh1, s0b, 0, 0, 0);
            s1b = __builtin_amdgcn_mfma_f32_16x16x32_bf16(Ah[ks], bl1, s1b, 0, 0, 0);
            s1b = __builtin_amdgcn_mfma_f32_16x16x32_bf16(Al[ks], bh1, s1b, 0, 0, 0);
        }
        float sv0[4], sv1[4];
        const bool okA = (u0 + tx) < ue, okB = (u0 + 16 + tx) < ue;
#pragma unroll
        for (int r = 0; r < 4; r++) {
            sv0[r] = okA ? (s0a[r] + s1a[r]) : -1e30f;
            sv1[r] = okB ? (s0b[r] + s1b[r]) : -1e30f;
        }

        // ---- online softmax, fully within-wave (16-lane groups)
        float alpha[4];
#pragma unroll
        for (int r = 0; r < 4; r++) {
            float mx = fmaxf(sv0[r], sv1[r]);
            mx = fmaxf(mx, __shfl_xor(mx, 1));
            mx = fmaxf(mx, __shfl_xor(mx, 2));
            mx = fmaxf(mx, __shfl_xor(mx, 4));
            mx = fmaxf(mx, __shfl_xor(mx, 8));
            float mn = fmaxf(m_s[r], mx);
            alpha[r] = __expf(m_s[r] - mn);
            float p0 = __expf(sv0[r] - mn);
            float p1 = __expf(sv1[r] - mn);
            sP[w * 16 + quad * 4 + r][tx]      = f2bf(p0);
            sP[w * 16 + quad * 4 + r][16 + tx] = f2bf(p1);
            float s = p0 + p1;
            s += __shfl_xor(s, 1);
            s += __shfl_xor(s, 2);
            s += __shfl_xor(s, 4);
            s += __shfl_xor(s, 8);
            l_s[r] = l_s[r] * alpha[r] + s;
            m_s[r] = mn;
        }
        f32x4 alv = {alpha[0], alpha[1], alpha[2], alpha[3]};
#pragma unroll
        for (int j = 0; j < 12; j++) accO[j] *= alv;
        __syncthreads();

        // ---- PV: O += P * H, K=32 (one MFMA k-step), hi-H only
        bf16x8 pa = *(const bf16x8*)&sP[w * 16 + tx][quad * 8];
#pragma unroll
        for (int j = 0; j < 12; j++) {
            bf16x8 hb = *(const bf16x8*)&sHt[j * 16 + tx][quad * 8];
            accO[j] = __builtin_amdgcn_mfma_f32_16x16x32_bf16(pa, hb, accO[j], 0, 0, 0);
        }
    }

#pragma unroll
    for (int r = 0; r < 4; r++) {
        int c = c0 + w * 16 + quad * 4 + r;
        if (c < CN_) {
            float* orow = Op + (((size_t)sp * B_ + b) * CN_ + c) * HD_;
#pragma unroll
            for (int j = 0; j < 12; j++) orow[j * 16 + tx] = accO[j][r];
            if (tx == 0) {
                size_t mi = ((size_t)sp * B_ + b) * CN_ + c;
                Ml[mi] = m_s[r];
                Ll[mi] = l_s[r];
            }
        }
    }
}

// ---------------------------------------------------------------------------
// K4: merge the two u-half partials.
// ---------------------------------------------------------------------------
__global__ __launch_bounds__(192) void k_merge(const float* __restrict__ Op,
                                               const float* __restrict__ Ml,
                                               const float* __restrict__ Ll,
                                               float* __restrict__ out) {
    const int c = blockIdx.x, b = blockIdx.y, h = threadIdx.x;
    const size_t i0 = (size_t)b * CN_ + c;
    const size_t i1 = (size_t)B_ * CN_ + i0;
    float m0 = Ml[i0], m1 = Ml[i1];
    float l0 = Ll[i0], l1 = Ll[i1];
    float M  = fmaxf(m0, m1);
    float e0 = __expf(m0 - M), e1 = __expf(m1 - M);
    float L  = l0 * e0 + l1 * e1;
    float o0 = Op[i0 * HD_ + h], o1 = Op[i1 * HD_ + h];
    out[i0 * HD_ + h] = (o0 * e0 + o1 * e1) / L;
}

// ---------------------------------------------------------------------------
extern "C" void kernel_launch(void* const* d_in, const int* in_sizes, int n_in,
                              void* d_out, int out_size, void* d_ws, size_t ws_size,
                              hipStream_t stream) {
    const float* X  = (const float*)d_in[0];
    const float* H  = (const float*)d_in[1];
    const float* W1 = (const float*)d_in[2];
    const float* W2 = (const float*)d_in[3];
    float* out = (float*)d_out;

    char* ws = (char*)d_ws;
    u16*   Ysh  = (u16*)(ws);                    //   8,478,720
    u16*   Ysl  = (u16*)(ws + 8478720);          //   8,478,720
    u16*   Hh   = (u16*)(ws + 16957440);         //  33,914,880
    u16*   Hl   = (u16*)(ws + 50872320);         //  33,914,880
    u16*   Hth  = (u16*)(ws + 84787200);         //  34,209,792
    u16*   Xth  = (u16*)(ws + 118996992);        //  17,301,504  (aliased by Op later)
    u16*   Xtl  = (u16*)(ws + 136298496);        //  17,301,504
    float* Op   = (float*)(ws + 118996992);      //  33,914,880  (aliases Xth+Xtl; k12 done first)
    u16*   W2h  = (u16*)(ws + 153600000);        //   1,081,344
    u16*   W2l  = (u16*)(ws + 154681344);        //   1,081,344
    u16*   W1th = (u16*)(ws + 155762688);        //      36,864
    u16*   W1tl = (u16*)(ws + 155799552);        //      36,864
    float* Ml   = (float*)(ws + 155836416);      //     176,640
    float* Ll   = (float*)(ws + 156013056);      //     176,640  -> end 156,189,696

    k0_h    <<<dim3(22, 3, B_), 256, 0, stream>>>(H, Hh, Hl, Hth);
    k0_x    <<<dim3(22, B_),    256, 0, stream>>>(X, Xth, Xtl);
    k0_w2   <<<dim3(1056),      256, 0, stream>>>(W2, W2h, W2l);
    k0_w1   <<<dim3(72),        256, 0, stream>>>(W1, W1th, W1tl);
    k12_mfma<<<dim3(384),       256, 0, stream>>>(W2h, W2l, Xth, Xtl, W1th, W1tl, Ysh, Ysl);
    k3_mfma <<<dim3(512),       384, 0, stream>>>(Ysh, Ysl, Hh, Hl, Hth, Op, Ml, Ll);
    k_merge <<<dim3(CN_, B_),   192, 0, stream>>>(Op, Ml, Ll, out);
}